// Round 16
// baseline (3492.981 us; speedup 1.0000x reference)
//
#include <hip/hip_runtime.h>
#include <math.h>

#ifndef M_PI
#define M_PI 3.14159265358979323846
#endif

#define BBc 4
#define CCc 32
#define NRk 16
#define HHc 192
#define WWc 192
#define HWc 36864
#define DDi 1179648
#define M1c 12
#define EPSc 1e-5f

static const size_t DDs = (size_t)DDi;

// ---------------- workspace layout (floats) ----------------
#define SZ_T   ((size_t)4718592)       // B*C*HW  (= B*D)
#define SZ_ZC  ((size_t)589824)        // B*C*H*12*2
#define SZ_ZF  ((size_t)73728)         // B*C*24*12*2
#define SZ_WT  ((size_t)589824)        // 24*12*32*32*2
#define SZ_TAB ((size_t)4992)          // 13*192*2

#define OFF_XC   ((size_t)0)                  // xcur      (B*D)
#define OFF_XI   (OFF_XC + SZ_T)              // xi        (B*D floats)
#define OFF_F    (OFF_XI + SZ_T)              // F history [slot][B][D], 5 slots (SoA)
#define OFF_G    (OFF_F + 5 * SZ_T)           // G history BF16 [slot][B][D], 5 slots (half region)
#define OFF_ZC   (OFF_G + 5 * SZ_T)
#define OFF_ZF   (OFF_ZC + SZ_ZC)
#define OFF_MO   (OFF_ZF + SZ_ZF)
#define OFF_TM   (OFF_MO + SZ_ZF)
#define OFF_WT   (OFF_TM + SZ_ZC)
#define OFF_TAB  (OFF_WT + SZ_WT)
#define OFF_STAT (OFF_TAB + SZ_TAB)
// total ~223.3 MiB (fits ws). setup scratch aliases G region:
#define A_XI0  OFF_G                   // B*16*HW (dead before first f7g write)
// ew/eb (288 floats) live in the MO region during setup (dead until DFT chain)

// stats sublayout (floats within STAT region)
// [0..511] : 16 evals x 32  (gn1: e*32 + b*4 + g*2 + j ; gn2: e*32 + 16 + ...)
#define ST_INJ   512   // 16
#define ST_BN    528   // 64
#define ST_GRAM  592   // 60  (4 batches x 15 packed lower-tri, PERSISTENT)
#define ST_ALPHA 652   // 20
#define ST_TOTAL 672

// bf16 helpers (RNE)
__device__ __forceinline__ float bf2f(unsigned short u) {
    return __uint_as_float(((unsigned int)u) << 16);
}
__device__ __forceinline__ unsigned short f2bf(float f) {
    unsigned int u = __float_as_uint(f);
    unsigned int r = (u + 0x7FFFu + ((u >> 16) & 1u)) >> 16;
    return (unsigned short)r;
}

// ---------------- small utility kernels ----------------
__global__ void k_zero(float* p, int n) {
    int i = blockIdx.x * blockDim.x + threadIdx.x;
    if (i < n) p[i] = 0.f;
}

__global__ void k_tables(float* tab) {
    int i = blockIdx.x * blockDim.x + threadIdx.x;  // 13*192
    if (i < 13 * 192) {
        int k = i / 192, x = i % 192;
        double th = 2.0 * M_PI * (double)(k * x) / 192.0;
        tab[i] = (float)cos(th);
        tab[13 * 192 + i] = (float)sin(th);
    }
}

// transpose spectral weights to wt[j][ky][i][o][2], j in 0..23
__global__ void k_wt(const float* __restrict__ w1r, const float* __restrict__ w1i,
                     const float* __restrict__ w2r, const float* __restrict__ w2i,
                     float* __restrict__ wt) {
    int idx = blockIdx.x * 256 + threadIdx.x;  // 24*12*32*32
    if (idx >= 24 * 12 * 1024) return;
    int o = idx & 31;
    int i = (idx >> 5) & 31;
    int ky = (idx >> 10) % 12;
    int j = idx / (12 * 1024);
    const float* wr;
    const float* wi;
    int x;
    if (j < 12) { wr = w1r; wi = w1i; x = j; }
    else        { wr = w2r; wi = w2i; x = j - 12; }
    int src = ((i * 32 + o) * 12 + x) * 12 + ky;
    size_t dst = (((size_t)j * 12 + ky) * 1024 + i * 32 + o) * 2;
    wt[dst] = wr[src];
    wt[dst + 1] = wi[src];
}

// effective single-channel conv weights: ew[n][t] = sum_c cw[n][c][t]*fc0w[c],
// eb[n][t] = sum_c cw[n][c][t]*fc0b[c]   (rank-1 xin = x*fc0w + fc0b)
__global__ void k_ew(const float* __restrict__ cw, const float* __restrict__ fc0w,
                     const float* __restrict__ fc0b, float* __restrict__ ewb) {
    int i = threadIdx.x;  // 144 = 16 n x 9 taps
    if (i >= 144) return;
    int n = i / 9, t = i % 9;
    float ew = 0.f, eb = 0.f;
    for (int c = 0; c < 32; ++c) {
        float k = cw[(size_t)(n * CCc + c) * 9 + t];
        ew += k * fc0w[c];
        eb += k * fc0b[c];
    }
    ewb[i] = ew;
    ewb[144 + i] = eb;
}

// conv3x3 SAME on rank-1 input via effective kernels: 1 channel in, 16 out.
// block per (b,h), 192 threads (one per w). Boundary: whole-xin zeroing => per-tap mask.
__global__ __launch_bounds__(192) void k_conv2(const float* __restrict__ x,
                                               const float* __restrict__ ewb,
                                               float* __restrict__ xi0) {
    int b = blockIdx.x / HHc, h = blockIdx.x % HHc;
    __shared__ float sm[3 * 194];
    __shared__ float ews[144], ebs[144];
    int w = threadIdx.x;
    for (int i = threadIdx.x; i < 3 * 194; i += 192) {
        int r = i / 194, col = (i % 194) - 1;
        int hr = h + r - 1;
        float v = 0.f;
        if (hr >= 0 && hr < HHc && col >= 0 && col < WWc)
            v = x[(size_t)b * HWc + (size_t)hr * WWc + col];
        sm[i] = v;
    }
    if (threadIdx.x < 144) {
        ews[threadIdx.x] = ewb[threadIdx.x];
        ebs[threadIdx.x] = ewb[144 + threadIdx.x];
    }
    __syncthreads();
    float xv[9], mk[9];
#pragma unroll
    for (int r = 0; r < 3; ++r) {
        int hr = h + r - 1;
        bool rok = (hr >= 0 && hr < HHc);
#pragma unroll
        for (int dx = 0; dx < 3; ++dx) {
            int wx = w + dx - 1;
            bool ok = rok && (wx >= 0) && (wx < WWc);
            xv[r * 3 + dx] = sm[r * 194 + (w + dx)];
            mk[r * 3 + dx] = ok ? 1.f : 0.f;
        }
    }
#pragma unroll
    for (int n = 0; n < 16; ++n) {
        float acc = 0.f;
#pragma unroll
        for (int t = 0; t < 9; ++t)
            acc += ews[n * 9 + t] * xv[t] + mk[t] * ebs[n * 9 + t];
        xi0[((size_t)b * NRk + n) * HWc + (size_t)h * WWc + w] = acc;
    }
}

// generic contiguous-bin sum/sumsq with atomics
__global__ void k_binstats(const float* __restrict__ src, float* __restrict__ stats,
                           int binsize, int blocksPerBin) {
    int bin = blockIdx.x / blocksPerBin, sub = blockIdx.x % blocksPerBin;
    const float* p = src + (size_t)bin * binsize;
    float s = 0.f, q = 0.f;
    for (int i = sub * blockDim.x + threadIdx.x; i < binsize; i += blocksPerBin * blockDim.x) {
        float v = p[i];
        s += v;
        q += v * v;
    }
    for (int o = 32; o; o >>= 1) { s += __shfl_down(s, o); q += __shfl_down(q, o); }
    __shared__ float rs[4], rq[4];
    int wid = threadIdx.x >> 6, lane = threadIdx.x & 63;
    if (lane == 0) { rs[wid] = s; rq[wid] = q; }
    __syncthreads();
    if (threadIdx.x == 0) {
        int nw = blockDim.x >> 6;
        float ts = 0.f, tq = 0.f;
        for (int i = 0; i < nw; ++i) { ts += rs[i]; tq += rq[i]; }
        atomicAdd(&stats[bin * 2], ts);
        atomicAdd(&stats[bin * 2 + 1], tq);
    }
}

// xi = sigmoid(q_w * GN(xi0) + q_b), block per (b,h), register-blocked (fp32)
__global__ __launch_bounds__(192) void k_xi(const float* __restrict__ xi0,
                                            const float* __restrict__ stats,
                                            const float* __restrict__ gnw, const float* __restrict__ gnb,
                                            const float* __restrict__ qw, const float* __restrict__ qb,
                                            float* __restrict__ xi) {
    int b = blockIdx.x / HHc, h = blockIdx.x % HHc;
    int w = threadIdx.x;
    const float Ninv = 1.f / (8.f * HWc);
    float tn[16];
#pragma unroll
    for (int n = 0; n < 16; ++n) {
        int g = n >> 3;
        float su = stats[(b * 2 + g) * 2], sq = stats[(b * 2 + g) * 2 + 1];
        float mu = su * Ninv;
        float var = sq * Ninv - mu * mu;
        float inv = rsqrtf(var + EPSc);
        float v = xi0[((size_t)b * NRk + n) * HWc + (size_t)h * WWc + w];
        tn[n] = (v - mu) * inv * gnw[n] + gnb[n];
    }
#pragma unroll
    for (int d = 0; d < 32; ++d) {
        float acc = qb[d];
        const float* row = qw + d * 16;
#pragma unroll
        for (int n = 0; n < 16; ++n) acc += tn[n] * row[n];
        xi[((size_t)b * CCc + d) * HWc + (size_t)h * WWc + w] = 1.f / (1.f + expf(-acc));
    }
}

// ---------------- DFT chain (z input: [b][D], batch stride D) ----------------
// plain forward DFT along W (used for eval 1 where z = F0 directly)
__global__ __launch_bounds__(192) void k_dftw(const float* __restrict__ z0,
                                              const float* __restrict__ tab,
                                              float* __restrict__ Zc) {
    int bc = blockIdx.x / 24;
    int hg = blockIdx.x % 24;
    int b = bc >> 5, c = bc & 31;
    const float* zp = z0 + (size_t)b * DDs + (size_t)c * HWc + (size_t)hg * 8 * WWc;
    __shared__ float rows[8 * 196];
    __shared__ float tb[24 * 196];
    const float4* zq = (const float4*)zp;
    for (int i4 = threadIdx.x; i4 < 384; i4 += 192) {
        float4 v = zq[i4];
        int r = i4 / 48, col = (i4 % 48) * 4;
        *(float4*)&rows[r * 196 + col] = v;
    }
    for (int i4 = threadIdx.x; i4 < 1152; i4 += 192) {
        int rr = i4 / 48, col = (i4 % 48) * 4;
        const float* src = (rr < 12) ? &tab[rr * 192 + col] : &tab[2496 + (rr - 12) * 192 + col];
        *(float4*)&tb[rr * 196 + col] = *(const float4*)src;
    }
    __syncthreads();
    int t = threadIdx.x;
    int r = t / 24, q = t % 24, ky = q >> 1, isim = q & 1;
    const float* tbp = tb + (isim ? (12 + ky) * 196 : ky * 196);
    const float* rowp = rows + r * 196;
    float a0 = 0.f, a1 = 0.f, a2 = 0.f, a3 = 0.f;
#pragma unroll
    for (int w2 = 0; w2 < WWc; w2 += 4) {
        a0 += rowp[w2] * tbp[w2];
        a1 += rowp[w2 + 1] * tbp[w2 + 1];
        a2 += rowp[w2 + 2] * tbp[w2 + 2];
        a3 += rowp[w2 + 3] * tbp[w2 + 3];
    }
    float acc = (a0 + a1) + (a2 + a3);
    if (isim) acc = -acc;
    int h = hg * 8 + r;
    Zc[(((size_t)bc * HHc + h) * M1c + ky) * 2 + isim] = acc;
}

// FUSED xnew + forward W-DFT
__global__ __launch_bounds__(192) void k_dftwx(const float* __restrict__ F,
                                               const float* __restrict__ alpha,
                                               const float* __restrict__ tab,
                                               float* __restrict__ xc,
                                               float* __restrict__ Zc) {
    int bc = blockIdx.x / 24;
    int hg = blockIdx.x % 24;
    int b = bc >> 5, c = bc & 31;
    size_t elem = (size_t)b * DDs + (size_t)c * HWc + (size_t)hg * 8 * WWc;
    int off4 = (int)(elem >> 2);
    const int sq4 = 1179648;  // SZ_T/4
    float a0 = alpha[b * 5], a1 = alpha[b * 5 + 1], a2 = alpha[b * 5 + 2];
    float a3 = alpha[b * 5 + 3], a4 = alpha[b * 5 + 4];
    __shared__ float rows[8 * 196];
    __shared__ float tb[24 * 196];
    const float4* F4 = (const float4*)F;
    float4* xc4 = (float4*)xc;
    for (int i4 = threadIdx.x; i4 < 384; i4 += 192) {
        float4 f0 = F4[off4 + i4];
        float4 f1 = F4[sq4 + off4 + i4];
        float4 f2 = F4[2 * sq4 + off4 + i4];
        float4 f3 = F4[3 * sq4 + off4 + i4];
        float4 f4v = F4[4 * sq4 + off4 + i4];
        float4 v;
        v.x = a0 * f0.x + a1 * f1.x + a2 * f2.x + a3 * f3.x + a4 * f4v.x;
        v.y = a0 * f0.y + a1 * f1.y + a2 * f2.y + a3 * f3.y + a4 * f4v.y;
        v.z = a0 * f0.z + a1 * f1.z + a2 * f2.z + a3 * f3.z + a4 * f4v.z;
        v.w = a0 * f0.w + a1 * f1.w + a2 * f2.w + a3 * f3.w + a4 * f4v.w;
        xc4[off4 + i4] = v;
        int r = i4 / 48, col = (i4 % 48) * 4;
        *(float4*)&rows[r * 196 + col] = v;
    }
    for (int i4 = threadIdx.x; i4 < 1152; i4 += 192) {
        int rr = i4 / 48, col = (i4 % 48) * 4;
        const float* src = (rr < 12) ? &tab[rr * 192 + col] : &tab[2496 + (rr - 12) * 192 + col];
        *(float4*)&tb[rr * 196 + col] = *(const float4*)src;
    }
    __syncthreads();
    int t = threadIdx.x;
    int r = t / 24, q = t % 24, ky = q >> 1, isim = q & 1;
    const float* tbp = tb + (isim ? (12 + ky) * 196 : ky * 196);
    const float* rowp = rows + r * 196;
    float a0s = 0.f, a1s = 0.f, a2s = 0.f, a3s = 0.f;
#pragma unroll
    for (int w2 = 0; w2 < WWc; w2 += 4) {
        a0s += rowp[w2] * tbp[w2];
        a1s += rowp[w2 + 1] * tbp[w2 + 1];
        a2s += rowp[w2 + 2] * tbp[w2 + 2];
        a3s += rowp[w2 + 3] * tbp[w2 + 3];
    }
    float acc = (a0s + a1s) + (a2s + a3s);
    if (isim) acc = -acc;
    int h = hg * 8 + r;
    Zc[(((size_t)bc * HHc + h) * M1c + ky) * 2 + isim] = acc;
}

__global__ __launch_bounds__(256) void k_dfth(const float* __restrict__ Zc,
                                              const float* __restrict__ tab,
                                              float* __restrict__ ZF) {
    int bc = blockIdx.x;
    __shared__ float zp[HHc * 12 * 2];
    const float4* src = (const float4*)(Zc + (size_t)bc * HHc * 12 * 2);
    for (int i4 = threadIdx.x; i4 < HHc * 6; i4 += 256)
        *(float4*)&zp[i4 * 4] = src[i4];
    __syncthreads();
    const float* tc = tab;
    const float* ts = tab + 2496;
    for (int oidx = threadIdx.x; oidx < 288; oidx += 256) {
        int j = oidx / 12, ky = oidx % 12;
        int k = (j < 12) ? j : 24 - j;
        float sgn = (j < 12) ? 1.f : -1.f;
        float re0 = 0.f, im0 = 0.f, re1 = 0.f, im1 = 0.f;
        for (int h = 0; h < HHc; h += 2) {
            float zr = zp[(h * 12 + ky) * 2], zi = zp[(h * 12 + ky) * 2 + 1];
            float cv = tc[k * 192 + h], sv = sgn * ts[k * 192 + h];
            re0 += zr * cv + zi * sv;
            im0 += zi * cv - zr * sv;
            float zr1 = zp[((h + 1) * 12 + ky) * 2], zi1 = zp[((h + 1) * 12 + ky) * 2 + 1];
            float cv1 = tc[k * 192 + h + 1], sv1 = sgn * ts[k * 192 + h + 1];
            re1 += zr1 * cv1 + zi1 * sv1;
            im1 += zi1 * cv1 - zr1 * sv1;
        }
        ZF[((size_t)bc * 288 + oidx) * 2] = re0 + re1;
        ZF[((size_t)bc * 288 + oidx) * 2 + 1] = im0 + im1;
    }
}

__global__ __launch_bounds__(64) void k_mix(const float* __restrict__ ZF,
                                            const float* __restrict__ wt,
                                            float* __restrict__ MO) {
    int b = blockIdx.x / 288, mode = blockIdx.x % 288;
    __shared__ float zin[64];
    int t = threadIdx.x;
    zin[t] = ZF[(((size_t)b * 32 + (t >> 1)) * 288 + mode) * 2 + (t & 1)];
    __syncthreads();
    int o = t >> 1, ri = t & 1;
    const float* wp = wt + (size_t)mode * 2048;
    float acc = 0.f;
#pragma unroll 8
    for (int i = 0; i < 32; ++i) {
        float ar = zin[2 * i], ai = zin[2 * i + 1];
        float wr = wp[(i * 32 + o) * 2], wi = wp[(i * 32 + o) * 2 + 1];
        acc += ri ? (ar * wi + ai * wr) : (ar * wr - ai * wi);
    }
    MO[(((size_t)b * 32 + o) * 288 + mode) * 2 + ri] = acc;
}

__global__ __launch_bounds__(256) void k_idfth(const float* __restrict__ MO,
                                               const float* __restrict__ tab,
                                               float* __restrict__ Tm) {
    int bo = blockIdx.x;
    __shared__ float mp[576];
    const float4* src = (const float4*)(MO + (size_t)bo * 576);
    for (int i4 = threadIdx.x; i4 < 144; i4 += 256)
        *(float4*)&mp[i4 * 4] = src[i4];
    __syncthreads();
    const float* tc = tab;
    const float* ts = tab + 2496;
    const float scale = 1.f / 192.f;
    for (int oidx = threadIdx.x; oidx < HHc * 12; oidx += 256) {
        int h = oidx / 12, ky = oidx % 12;
        float re = 0.f, im = 0.f;
#pragma unroll
        for (int j = 0; j < 24; ++j) {
            int k = (j < 12) ? j : 24 - j;
            float sgn = (j < 12) ? 1.f : -1.f;
            float mr = mp[(j * 12 + ky) * 2], mi = mp[(j * 12 + ky) * 2 + 1];
            float cv = tc[k * 192 + h], sv = sgn * ts[k * 192 + h];
            re += mr * cv - mi * sv;
            im += mr * sv + mi * cv;
        }
        Tm[((size_t)bo * HHc + h) * 24 + ky * 2] = re * scale;
        Tm[((size_t)bo * HHc + h) * 24 + ky * 2 + 1] = im * scale;
    }
}

// iDFT-W + y2(1x1 conv) + exact gelu + xi add -> sbuf (= dest F slot); gn1 stats.
// ONE block per (b,h), 384 threads = 48 w-quads x 8 o-quads (z staged once).
// LDS: zl 196 (float4-clean), w0s 36, tms 28. z0 == nullptr => z = 0 (eval 0).
__global__ __launch_bounds__(384) void k_f5(const float* __restrict__ z0,
                                            const float* __restrict__ Tm,
                                            const float* __restrict__ xi,
                                            const float* __restrict__ w0w,
                                            const float* __restrict__ w0b,
                                            const float* __restrict__ tab,
                                            float* __restrict__ sbuf,
                                            float* __restrict__ stats_e,
                                            int use_y1) {
    int h = blockIdx.x % HHc;
    int b = blockIdx.x / HHc;
    __shared__ float zl[32 * 196];     // padded stride 196 (float4-clean)
    __shared__ float w0s[32 * 36];     // padded stride 36
    __shared__ float tms[32 * 28];     // padded stride 28
    __shared__ float red[6][4];
    int tid = threadIdx.x;
    if (z0) {
        const float* zp = z0 + (size_t)b * DDs + (size_t)h * WWc;
        for (int i4 = tid; i4 < 32 * 48; i4 += 384) {
            int c = i4 / 48, q = (i4 % 48) * 4;
            float4 v = *(const float4*)(zp + (size_t)c * HWc + q);
            *(float4*)&zl[c * 196 + q] = v;
        }
        for (int i4 = tid; i4 < 256; i4 += 384) {
            int oo = i4 / 8, q = (i4 % 8) * 4;
            *(float4*)&w0s[oo * 36 + q] = *(const float4*)(w0w + oo * 32 + q);
        }
    }
    if (use_y1) {
        for (int i4 = tid; i4 < 192; i4 += 384) {
            int oo = i4 / 6, q = (i4 % 6) * 4;
            *(float4*)&tms[oo * 28 + q] =
                *(const float4*)(Tm + (((size_t)b * 32 + oo) * HHc + h) * 24 + q);
        }
    }
    __syncthreads();

    int wq = tid >> 3;          // 0..47
    int oq = tid & 7;           // 0..7
    int w4 = wq * 4;
    int o0 = oq * 4;            // o base (0..28)
    int grp = oq >> 2;          // GN group (all 4 o of this thread share it)
    const float Winv = 1.f / 192.f;
    float acc[4][4];
#pragma unroll
    for (int oo = 0; oo < 4; ++oo) {
        float bbv = w0b[o0 + oo];
#pragma unroll
        for (int k = 0; k < 4; ++k) acc[oo][k] = bbv;
    }
    if (use_y1) {
#pragma unroll
        for (int oo = 0; oo < 4; ++oo) {
            float t0 = tms[(o0 + oo) * 28];
#pragma unroll
            for (int k = 0; k < 4; ++k) acc[oo][k] += t0 * Winv;
        }
#pragma unroll
        for (int ky = 1; ky <= 11; ++ky) {
            float4 c4 = *(const float4*)(tab + ky * 192 + w4);
            float4 s4 = *(const float4*)(tab + 2496 + ky * 192 + w4);
            float sc = 2.f * Winv;
#pragma unroll
            for (int oo = 0; oo < 4; ++oo) {
                float tre = tms[(o0 + oo) * 28 + 2 * ky] * sc;
                float tim = tms[(o0 + oo) * 28 + 2 * ky + 1] * sc;
                acc[oo][0] += tre * c4.x - tim * s4.x;
                acc[oo][1] += tre * c4.y - tim * s4.y;
                acc[oo][2] += tre * c4.z - tim * s4.z;
                acc[oo][3] += tre * c4.w - tim * s4.w;
            }
        }
    }
    if (z0) {
#pragma unroll 8
        for (int c = 0; c < 32; ++c) {
            float4 zq4 = *(const float4*)&zl[c * 196 + w4];
#pragma unroll
            for (int oo = 0; oo < 4; ++oo) {
                float wv = w0s[(o0 + oo) * 36 + c];
                acc[oo][0] += zq4.x * wv;
                acc[oo][1] += zq4.y * wv;
                acc[oo][2] += zq4.z * wv;
                acc[oo][3] += zq4.w * wv;
            }
        }
    }
    float s = 0.f, q = 0.f;
#pragma unroll
    for (int oo = 0; oo < 4; ++oo) {
        int o = o0 + oo;
        size_t gi = (size_t)b * DDs + (size_t)o * HWc + (size_t)h * WWc + w4;
        float4 x4 = *(const float4*)(xi + gi);
        float4 out4;
        float* op = (float*)&out4;
        const float* xp = (const float*)&x4;
#pragma unroll
        for (int k = 0; k < 4; ++k) {
            float v = acc[oo][k];
            float u = 0.5f * v * (1.f + erff(v * 0.70710678118654752f));
            float sv = xp[k] + u;
            op[k] = sv;
            s += sv;
            q += sv * sv;
        }
        *(float4*)(sbuf + gi) = out4;
    }
    float s0 = (grp == 0) ? s : 0.f, q0 = (grp == 0) ? q : 0.f;
    float s1 = (grp == 1) ? s : 0.f, q1 = (grp == 1) ? q : 0.f;
    for (int o = 32; o; o >>= 1) {
        s0 += __shfl_down(s0, o); q0 += __shfl_down(q0, o);
        s1 += __shfl_down(s1, o); q1 += __shfl_down(q1, o);
    }
    int wid = tid >> 6, lane = tid & 63;
    if (lane == 0) { red[wid][0] = s0; red[wid][1] = q0; red[wid][2] = s1; red[wid][3] = q1; }
    __syncthreads();
    if (tid == 0) {
        float a0 = 0, a1 = 0, a2 = 0, a3 = 0;
        for (int i = 0; i < 6; ++i) {
            a0 += red[i][0]; a1 += red[i][1]; a2 += red[i][2]; a3 += red[i][3];
        }
        atomicAdd(&stats_e[b * 4 + 0], a0);
        atomicAdd(&stats_e[b * 4 + 1], a1);
        atomicAdd(&stats_e[b * 4 + 2], a2);
        atomicAdd(&stats_e[b * 4 + 3], a3);
    }
}

// buf = relu(z + GN1(buf)) IN PLACE (float4); gn2 stats; zero gram row/col of slot
// grid: 8 bins x 144 blocks of 256 threads. z0 == nullptr => z = 0.
__global__ __launch_bounds__(256) void k_f6(const float* __restrict__ z0,
                                            float* buf,
                                            const float* __restrict__ stats_e,
                                            const float* __restrict__ n1w,
                                            const float* __restrict__ n1b,
                                            float* __restrict__ gram,
                                            int slot) {
    if (blockIdx.x == 0 && threadIdx.x < 20) {
        int j = threadIdx.x % 5, b2 = threadIdx.x / 5;
        int ii = slot > j ? slot : j, jj = slot > j ? j : slot;
        gram[b2 * 15 + ii * (ii + 1) / 2 + jj] = 0.f;
    }
    const int binq = 147456;         // quads per bin (16*HWc/4)
    const int BPB = 144;
    int bin = blockIdx.x / BPB, sub = blockIdx.x % BPB;
    float Nv = 16.f * HWc;
    float su = stats_e[bin * 2], sq = stats_e[bin * 2 + 1];
    float mu = su / Nv;
    float var = sq / Nv - mu * mu;
    float inv = rsqrtf(var + EPSc);
    const float4* z4 = (const float4*)z0;
    float4* b4 = (float4*)buf;
    float s = 0.f, q = 0.f;
    for (int i4 = sub * 256 + threadIdx.x; i4 < binq; i4 += BPB * 256) {
        int e4 = bin * binq + i4;
        int c = (bin & 1) * 16 + i4 / 9216;    // 9216 = HWc/4
        float w1 = inv * n1w[c];
        float b1 = n1b[c] - mu * w1;
        float4 sv = b4[e4];
        float4 zv = make_float4(0.f, 0.f, 0.f, 0.f);
        if (z0) zv = z4[e4];
        float4 r;
        r.x = zv.x + sv.x * w1 + b1; r.x = r.x > 0.f ? r.x : 0.f;
        r.y = zv.y + sv.y * w1 + b1; r.y = r.y > 0.f ? r.y : 0.f;
        r.z = zv.z + sv.z * w1 + b1; r.z = r.z > 0.f ? r.z : 0.f;
        r.w = zv.w + sv.w * w1 + b1; r.w = r.w > 0.f ? r.w : 0.f;
        b4[e4] = r;
        s += r.x + r.y + r.z + r.w;
        q += r.x * r.x + r.y * r.y + r.z * r.z + r.w * r.w;
    }
    for (int o = 32; o; o >>= 1) { s += __shfl_down(s, o); q += __shfl_down(q, o); }
    __shared__ float rs[4], rq[4];
    int wid = threadIdx.x >> 6, lane = threadIdx.x & 63;
    if (lane == 0) { rs[wid] = s; rq[wid] = q; }
    __syncthreads();
    if (threadIdx.x == 0) {
        atomicAdd((float*)&stats_e[16 + bin * 2], rs[0] + rs[1] + rs[2] + rs[3]);
        atomicAdd((float*)&stats_e[16 + bin * 2 + 1], rq[0] + rq[1] + rq[2] + rq[3]);
    }
}

// buf = GN2(buf) IN PLACE; if do_gram: G[slot] = bf16(buf - z); incremental Gram.
// grid: 4 b x 288 sub = 1152 blocks of 256. z0 == nullptr => z = 0.
__global__ __launch_bounds__(256) void k_f7g(float* buf,
                                             const float* __restrict__ z,
                                             const float* __restrict__ stats_e,
                                             const float* __restrict__ n2w,
                                             const float* __restrict__ n2b,
                                             unsigned short* __restrict__ G,
                                             float* __restrict__ gram,
                                             int slot, int do_gram) {
    int b = blockIdx.x / 288, sub = blockIdx.x % 288;
    const float Ninv = 1.f / (16.f * HWc);
    float su0 = stats_e[16 + b * 4], sq0 = stats_e[16 + b * 4 + 1];
    float mu0 = su0 * Ninv, inv0 = rsqrtf(sq0 * Ninv - mu0 * mu0 + EPSc);
    float su1 = stats_e[16 + b * 4 + 2], sq1 = stats_e[16 + b * 4 + 3];
    float mu1 = su1 * Ninv, inv1 = rsqrtf(sq1 * Ninv - mu1 * mu1 + EPSc);
    const int bq = 294912;   // quads per batch (DDi/4)
    const int sq4 = 1179648; // quads per G slot (SZ_T/4)
    float4* b4 = (float4*)buf;
    const float4* z4 = (const float4*)z;
    ushort4* GU = (ushort4*)G;
    float p0 = 0, p1 = 0, p2 = 0, p3 = 0, p4 = 0;
    for (int loc4 = sub * 256 + threadIdx.x; loc4 < bq; loc4 += 73728) {
        int e4 = b * bq + loc4;
        int c = loc4 / 9216;
        float mu = (c < 16) ? mu0 : mu1;
        float inv = (c < 16) ? inv0 : inv1;
        float wv = inv * n2w[c];
        float bv = n2b[c] - mu * wv;
        float4 r = b4[e4];
        float4 fn;
        fn.x = r.x * wv + bv;
        fn.y = r.y * wv + bv;
        fn.z = r.z * wv + bv;
        fn.w = r.w * wv + bv;
        b4[e4] = fn;
        if (do_gram) {
            float4 zv = make_float4(0.f, 0.f, 0.f, 0.f);
            if (z) zv = z4[e4];
            float4 g;
            g.x = fn.x - zv.x; g.y = fn.y - zv.y; g.z = fn.z - zv.z; g.w = fn.w - zv.w;
            ushort4 gw;
            gw.x = f2bf(g.x); gw.y = f2bf(g.y); gw.z = f2bf(g.z); gw.w = f2bf(g.w);
            GU[(size_t)slot * sq4 + e4] = gw;
            float4 gj[5];
#pragma unroll
            for (int j = 0; j < 5; ++j) {
                if (j == slot) { gj[j] = g; }
                else {
                    ushort4 u = GU[(size_t)j * sq4 + e4];
                    gj[j].x = bf2f(u.x); gj[j].y = bf2f(u.y);
                    gj[j].z = bf2f(u.z); gj[j].w = bf2f(u.w);
                }
            }
            p0 += g.x * gj[0].x + g.y * gj[0].y + g.z * gj[0].z + g.w * gj[0].w;
            p1 += g.x * gj[1].x + g.y * gj[1].y + g.z * gj[1].z + g.w * gj[1].w;
            p2 += g.x * gj[2].x + g.y * gj[2].y + g.z * gj[2].z + g.w * gj[2].w;
            p3 += g.x * gj[3].x + g.y * gj[3].y + g.z * gj[3].z + g.w * gj[3].w;
            p4 += g.x * gj[4].x + g.y * gj[4].y + g.z * gj[4].z + g.w * gj[4].w;
        }
    }
    if (!do_gram) return;
    float p[5] = {p0, p1, p2, p3, p4};
    __shared__ float red[4][5];
    int wid = threadIdx.x >> 6, lane = threadIdx.x & 63;
#pragma unroll
    for (int j = 0; j < 5; ++j) {
        float v = p[j];
        for (int o = 32; o; o >>= 1) v += __shfl_down(v, o);
        if (lane == 0) red[wid][j] = v;
    }
    __syncthreads();
    if (threadIdx.x == 0) {
#pragma unroll
        for (int j = 0; j < 5; ++j) {
            int ii = slot > j ? slot : j, jj = slot > j ? j : slot;
            atomicAdd(&gram[b * 15 + ii * (ii + 1) / 2 + jj],
                      red[0][j] + red[1][j] + red[2][j] + red[3][j]);
        }
    }
}

// ---------------- Anderson solve (tiny, separate) ----------------
__global__ void k_solve(const float* __restrict__ gram, float* __restrict__ alpha, int n) {
    int b = threadIdx.x;
    if (b >= BBc) return;
    float A[6][7];
    int nn = n + 1;
    for (int i = 0; i < nn; ++i)
        for (int j = 0; j <= nn; ++j) A[i][j] = 0.f;
    for (int j = 1; j < nn; ++j) { A[0][j] = 1.f; A[j][0] = 1.f; }
    for (int i = 0; i < n; ++i)
        for (int j = 0; j < n; ++j) {
            int ii = i > j ? i : j, jj = i > j ? j : i;
            float v = gram[b * 15 + ii * (ii + 1) / 2 + jj];
            A[i + 1][j + 1] = v + ((i == j) ? 1e-4f : 0.f);
        }
    A[0][nn] = 1.f;
    for (int col = 0; col < nn; ++col) {
        int piv = col;
        float best = fabsf(A[col][col]);
        for (int r2 = col + 1; r2 < nn; ++r2) {
            float av = fabsf(A[r2][col]);
            if (av > best) { best = av; piv = r2; }
        }
        if (piv != col)
            for (int c2 = 0; c2 <= nn; ++c2) {
                float tv = A[col][c2];
                A[col][c2] = A[piv][c2];
                A[piv][c2] = tv;
            }
        float d = A[col][col];
        for (int r2 = col + 1; r2 < nn; ++r2) {
            float f = A[r2][col] / d;
            for (int c2 = col; c2 <= nn; ++c2) A[r2][c2] -= f * A[col][c2];
        }
    }
    float sol[6];
    for (int r2 = nn - 1; r2 >= 0; --r2) {
        float v = A[r2][nn];
        for (int c2 = r2 + 1; c2 < nn; ++c2) v -= A[r2][c2] * sol[c2];
        sol[r2] = v / A[r2][r2];
    }
    for (int j = 0; j < 5; ++j) alpha[b * 5 + j] = (j < n) ? sol[j + 1] : 0.f;
}

// ---------------- final: BN stats + BN + fc1(gelu) + fc2 ----------------
__global__ __launch_bounds__(256) void k_bnstats(const float* __restrict__ z,
                                                 float* __restrict__ bstats) {
    const int BPB = 18;
    int c = blockIdx.x / BPB, sub = blockIdx.x % BPB;
    float s = 0.f, q = 0.f;
    for (int i = sub * 256 + threadIdx.x; i < BBc * HWc; i += BPB * 256) {
        int b = i / HWc, hw = i % HWc;
        float v = z[(size_t)b * DDs + (size_t)c * HWc + hw];
        s += v;
        q += v * v;
    }
    for (int o = 32; o; o >>= 1) { s += __shfl_down(s, o); q += __shfl_down(q, o); }
    __shared__ float rs[4], rq[4];
    int wid = threadIdx.x >> 6, lane = threadIdx.x & 63;
    if (lane == 0) { rs[wid] = s; rq[wid] = q; }
    __syncthreads();
    if (threadIdx.x == 0) {
        atomicAdd(&bstats[c * 2], rs[0] + rs[1] + rs[2] + rs[3]);
        atomicAdd(&bstats[c * 2 + 1], rq[0] + rq[1] + rq[2] + rq[3]);
    }
}

__global__ __launch_bounds__(192) void k_final(const float* __restrict__ z,
                                               const float* __restrict__ bstats,
                                               const float* __restrict__ bnw,
                                               const float* __restrict__ bnb,
                                               const float* __restrict__ fc1w,
                                               const float* __restrict__ fc1b,
                                               const float* __restrict__ fc2w,
                                               const float* __restrict__ fc2b,
                                               float* __restrict__ out) {
    int b = blockIdx.x / HHc, h = blockIdx.x % HHc;
    int w = threadIdx.x;
    const float Ninv = 1.f / ((float)BBc * HWc);
    float zv[32];
#pragma unroll
    for (int c = 0; c < 32; ++c) {
        float su = bstats[c * 2], sq = bstats[c * 2 + 1];
        float mu = su * Ninv;
        float var = sq * Ninv - mu * mu;
        float inv = rsqrtf(var + EPSc);
        float v = z[(size_t)b * DDs + (size_t)c * HWc + (size_t)h * WWc + w];
        zv[c] = (v - mu) * inv * bnw[c] + bnb[c];
    }
    float acc2 = fc2b[0];
#pragma unroll
    for (int o = 0; o < 32; ++o) {
        float a = fc1b[o];
        const float* row = fc1w + o * 32;
#pragma unroll
        for (int c = 0; c < 32; ++c) a += zv[c] * row[c];
        float g = 0.5f * a * (1.f + erff(a * 0.70710678118654752f));
        acc2 += fc2w[o] * g;
    }
    out[(size_t)b * HWc + (size_t)h * WWc + w] = acc2;
}

// ---------------- host ----------------
extern "C" void kernel_launch(void* const* d_in, const int* in_sizes, int n_in,
                              void* d_out, int out_size, void* d_ws, size_t ws_size,
                              hipStream_t stream) {
    (void)in_sizes; (void)n_in; (void)out_size; (void)ws_size;
    const float* x    = (const float*)d_in[0];
    const float* fc0w = (const float*)d_in[1];
    const float* fc0b = (const float*)d_in[2];
    const float* convw = (const float*)d_in[3];
    const float* gnw  = (const float*)d_in[4];
    const float* gnb  = (const float*)d_in[5];
    const float* qw   = (const float*)d_in[6];
    const float* qb   = (const float*)d_in[7];
    const float* sw1r = (const float*)d_in[8];
    const float* sw1i = (const float*)d_in[9];
    const float* sw2r = (const float*)d_in[10];
    const float* sw2i = (const float*)d_in[11];
    const float* w0w  = (const float*)d_in[12];
    const float* w0b  = (const float*)d_in[13];
    const float* n1w  = (const float*)d_in[14];
    const float* n1b  = (const float*)d_in[15];
    const float* n2w  = (const float*)d_in[16];
    const float* n2b  = (const float*)d_in[17];
    const float* bnw  = (const float*)d_in[18];
    const float* bnb  = (const float*)d_in[19];
    const float* fc1w = (const float*)d_in[20];
    const float* fc1b = (const float*)d_in[21];
    const float* fc2w = (const float*)d_in[22];
    const float* fc2b = (const float*)d_in[23];
    float* out = (float*)d_out;

    float* ws = (float*)d_ws;
    float* XC  = ws + OFF_XC;
    float* XIp = ws + OFF_XI;
    float* Fb  = ws + OFF_F;
    unsigned short* Gb16 = (unsigned short*)(ws + OFF_G);
    float* ZC  = ws + OFF_ZC;
    float* ZFp = ws + OFF_ZF;
    float* MOp = ws + OFF_MO;
    float* TM  = ws + OFF_TM;
    float* WT  = ws + OFF_WT;
    float* TAB = ws + OFF_TAB;
    float* ST  = ws + OFF_STAT;
    float* XI0 = ws + A_XI0;   // setup alias (inside G region, dead before first f7g)
    float* EWB = MOp;          // setup alias (MO region free until DFT chain)

    // tail of one f_block evaluation (after ZC is ready or skipped)
    // zin == nullptr means z == 0 exactly (eval 0).
    auto runtail = [&](const float* zin, int outslot, int use_y1, int evalIdx,
                       int do_gram) {
        float* dst = Fb + (size_t)outslot * SZ_T;
        if (use_y1) {
            k_dfth<<<BBc * CCc, 256, 0, stream>>>(ZC, TAB, ZFp);
            k_mix<<<BBc * 288, 64, 0, stream>>>(ZFp, WT, MOp);
            k_idfth<<<BBc * CCc, 256, 0, stream>>>(MOp, TAB, TM);
        }
        float* stats_e = ST + (size_t)evalIdx * 32;
        k_f5<<<BBc * HHc, 384, 0, stream>>>(zin, TM, XIp, w0w, w0b, TAB, dst,
                                            stats_e, use_y1);
        k_f6<<<8 * 144, 256, 0, stream>>>(zin, dst, stats_e, n1w, n1b,
                                          ST + ST_GRAM, outslot);
        k_f7g<<<4 * 288, 256, 0, stream>>>(dst, zin, stats_e, n2w, n2b, Gb16,
                                           ST + ST_GRAM, outslot, do_gram);
    };

    // setup
    k_tables<<<10, 256, 0, stream>>>(TAB);
    k_wt<<<(24 * 12 * 1024 + 255) / 256, 256, 0, stream>>>(sw1r, sw1i, sw2r, sw2i, WT);
    k_zero<<<3, 256, 0, stream>>>(ST, ST_TOTAL);
    k_ew<<<1, 192, 0, stream>>>(convw, fc0w, fc0b, EWB);
    k_conv2<<<BBc * HHc, 192, 0, stream>>>(x, EWB, XI0);
    k_binstats<<<8 * 36, 256, 0, stream>>>(XI0, ST + ST_INJ, 8 * HWc, 36);
    k_xi<<<BBc * HHc, 192, 0, stream>>>(XI0, ST + ST_INJ, gnw, gnb, qw, qb, XIp);

    // f0 = f(0) -> F0 (z == 0: no spectral path, no z reads), G0, Gram(0,*)
    runtail(nullptr, 0, 0, 0, 1);
    // f1 = f(F0): plain dftw on F0
    k_dftw<<<BBc * CCc * 24, 192, 0, stream>>>(Fb, TAB, ZC);
    runtail(Fb, 1, 1, 1, 1);

    // Anderson iterations k = 2..15: solve -> fused xnew+dftw -> rest
    for (int k = 2; k < 16; ++k) {
        int n = k < 5 ? k : 5;
        int slot = k % 5;
        k_solve<<<1, 64, 0, stream>>>(ST + ST_GRAM, ST + ST_ALPHA, n);
        k_dftwx<<<BBc * CCc * 24, 192, 0, stream>>>(Fb, ST + ST_ALPHA, TAB, XC, ZC);
        runtail(XC, slot, 1, k, (k < 15) ? 1 : 0);
    }

    // final z = F slot 0; BatchNorm + fc1(gelu) + fc2
    k_bnstats<<<32 * 18, 256, 0, stream>>>(Fb, ST + ST_BN);
    k_final<<<BBc * HHc, 192, 0, stream>>>(Fb, ST + ST_BN, bnw, bnb, fc1w, fc1b,
                                           fc2w, fc2b, out);
}

// Round 17
// 3478.652 us; speedup vs baseline: 1.0041x; 1.0041x over previous
//
#include <hip/hip_runtime.h>
#include <math.h>

#ifndef M_PI
#define M_PI 3.14159265358979323846
#endif

#define BBc 4
#define CCc 32
#define NRk 16
#define HHc 192
#define WWc 192
#define HWc 36864
#define DDi 1179648
#define M1c 12
#define EPSc 1e-5f

static const size_t DDs = (size_t)DDi;

// ---------------- workspace layout (floats) ----------------
#define SZ_T   ((size_t)4718592)       // B*C*HW  (= B*D)
#define SZ_ZC  ((size_t)589824)        // B*C*H*12*2
#define SZ_ZF  ((size_t)73728)         // B*C*24*12*2
#define SZ_WT  ((size_t)589824)        // 24*12*32*32*2
#define SZ_TAB ((size_t)4992)          // 13*192*2

#define OFF_XC   ((size_t)0)                  // xcur      (B*D)
#define OFF_XI   (OFF_XC + SZ_T)              // xi        (B*D floats)
#define OFF_F    (OFF_XI + SZ_T)              // F history [slot][B][D], 5 slots (SoA)
#define OFF_G    (OFF_F + 5 * SZ_T)           // G history BF16 [slot][B][D], 5 slots (half region)
#define OFF_ZC   (OFF_G + 5 * SZ_T)
#define OFF_ZF   (OFF_ZC + SZ_ZC)
#define OFF_MO   (OFF_ZF + SZ_ZF)
#define OFF_TM   (OFF_MO + SZ_ZF)
#define OFF_WT   (OFF_TM + SZ_ZC)
#define OFF_TAB  (OFF_WT + SZ_WT)
#define OFF_STAT (OFF_TAB + SZ_TAB)
// total ~223.3 MiB (fits ws). setup scratch aliases G region:
#define A_XI0  OFF_G                   // B*16*HW (dead before first f7g write)
// ew/eb (288 floats) live in the MO region during setup (dead until DFT chain)

// stats sublayout (floats within STAT region)
// [0..511] : 16 evals x 32  (gn1: e*32 + b*4 + g*2 + j ; gn2: e*32 + 16 + ...)
#define ST_INJ   512   // 16
#define ST_BN    528   // 64
#define ST_GRAM  592   // 60  (4 batches x 15 packed lower-tri, PERSISTENT)
#define ST_ALPHA 652   // 20
#define ST_TOTAL 672

// bf16 helpers (RNE)
__device__ __forceinline__ float bf2f(unsigned short u) {
    return __uint_as_float(((unsigned int)u) << 16);
}
__device__ __forceinline__ unsigned short f2bf(float f) {
    unsigned int u = __float_as_uint(f);
    unsigned int r = (u + 0x7FFFu + ((u >> 16) & 1u)) >> 16;
    return (unsigned short)r;
}

// ---------------- small utility kernels ----------------
__global__ void k_zero(float* p, int n) {
    int i = blockIdx.x * blockDim.x + threadIdx.x;
    if (i < n) p[i] = 0.f;
}

__global__ void k_tables(float* tab) {
    int i = blockIdx.x * blockDim.x + threadIdx.x;  // 13*192
    if (i < 13 * 192) {
        int k = i / 192, x = i % 192;
        double th = 2.0 * M_PI * (double)(k * x) / 192.0;
        tab[i] = (float)cos(th);
        tab[13 * 192 + i] = (float)sin(th);
    }
}

// transpose spectral weights to wt[j][ky][i][o][2], j in 0..23
__global__ void k_wt(const float* __restrict__ w1r, const float* __restrict__ w1i,
                     const float* __restrict__ w2r, const float* __restrict__ w2i,
                     float* __restrict__ wt) {
    int idx = blockIdx.x * 256 + threadIdx.x;  // 24*12*32*32
    if (idx >= 24 * 12 * 1024) return;
    int o = idx & 31;
    int i = (idx >> 5) & 31;
    int ky = (idx >> 10) % 12;
    int j = idx / (12 * 1024);
    const float* wr;
    const float* wi;
    int x;
    if (j < 12) { wr = w1r; wi = w1i; x = j; }
    else        { wr = w2r; wi = w2i; x = j - 12; }
    int src = ((i * 32 + o) * 12 + x) * 12 + ky;
    size_t dst = (((size_t)j * 12 + ky) * 1024 + i * 32 + o) * 2;
    wt[dst] = wr[src];
    wt[dst + 1] = wi[src];
}

// effective single-channel conv weights: ew[n][t] = sum_c cw[n][c][t]*fc0w[c],
// eb[n][t] = sum_c cw[n][c][t]*fc0b[c]   (rank-1 xin = x*fc0w + fc0b)
__global__ void k_ew(const float* __restrict__ cw, const float* __restrict__ fc0w,
                     const float* __restrict__ fc0b, float* __restrict__ ewb) {
    int i = threadIdx.x;  // 144 = 16 n x 9 taps
    if (i >= 144) return;
    int n = i / 9, t = i % 9;
    float ew = 0.f, eb = 0.f;
    for (int c = 0; c < 32; ++c) {
        float k = cw[(size_t)(n * CCc + c) * 9 + t];
        ew += k * fc0w[c];
        eb += k * fc0b[c];
    }
    ewb[i] = ew;
    ewb[144 + i] = eb;
}

// conv3x3 SAME on rank-1 input via effective kernels: 1 channel in, 16 out.
// block per (b,h), 192 threads (one per w). Boundary: whole-xin zeroing => per-tap mask.
__global__ __launch_bounds__(192) void k_conv2(const float* __restrict__ x,
                                               const float* __restrict__ ewb,
                                               float* __restrict__ xi0) {
    int b = blockIdx.x / HHc, h = blockIdx.x % HHc;
    __shared__ float sm[3 * 194];
    __shared__ float ews[144], ebs[144];
    int w = threadIdx.x;
    for (int i = threadIdx.x; i < 3 * 194; i += 192) {
        int r = i / 194, col = (i % 194) - 1;
        int hr = h + r - 1;
        float v = 0.f;
        if (hr >= 0 && hr < HHc && col >= 0 && col < WWc)
            v = x[(size_t)b * HWc + (size_t)hr * WWc + col];
        sm[i] = v;
    }
    if (threadIdx.x < 144) {
        ews[threadIdx.x] = ewb[threadIdx.x];
        ebs[threadIdx.x] = ewb[144 + threadIdx.x];
    }
    __syncthreads();
    float xv[9], mk[9];
#pragma unroll
    for (int r = 0; r < 3; ++r) {
        int hr = h + r - 1;
        bool rok = (hr >= 0 && hr < HHc);
#pragma unroll
        for (int dx = 0; dx < 3; ++dx) {
            int wx = w + dx - 1;
            bool ok = rok && (wx >= 0) && (wx < WWc);
            xv[r * 3 + dx] = sm[r * 194 + (w + dx)];
            mk[r * 3 + dx] = ok ? 1.f : 0.f;
        }
    }
#pragma unroll
    for (int n = 0; n < 16; ++n) {
        float acc = 0.f;
#pragma unroll
        for (int t = 0; t < 9; ++t)
            acc += ews[n * 9 + t] * xv[t] + mk[t] * ebs[n * 9 + t];
        xi0[((size_t)b * NRk + n) * HWc + (size_t)h * WWc + w] = acc;
    }
}

// generic contiguous-bin sum/sumsq with atomics
__global__ void k_binstats(const float* __restrict__ src, float* __restrict__ stats,
                           int binsize, int blocksPerBin) {
    int bin = blockIdx.x / blocksPerBin, sub = blockIdx.x % blocksPerBin;
    const float* p = src + (size_t)bin * binsize;
    float s = 0.f, q = 0.f;
    for (int i = sub * blockDim.x + threadIdx.x; i < binsize; i += blocksPerBin * blockDim.x) {
        float v = p[i];
        s += v;
        q += v * v;
    }
    for (int o = 32; o; o >>= 1) { s += __shfl_down(s, o); q += __shfl_down(q, o); }
    __shared__ float rs[4], rq[4];
    int wid = threadIdx.x >> 6, lane = threadIdx.x & 63;
    if (lane == 0) { rs[wid] = s; rq[wid] = q; }
    __syncthreads();
    if (threadIdx.x == 0) {
        int nw = blockDim.x >> 6;
        float ts = 0.f, tq = 0.f;
        for (int i = 0; i < nw; ++i) { ts += rs[i]; tq += rq[i]; }
        atomicAdd(&stats[bin * 2], ts);
        atomicAdd(&stats[bin * 2 + 1], tq);
    }
}

// xi = sigmoid(q_w * GN(xi0) + q_b), block per (b,h), register-blocked (fp32)
__global__ __launch_bounds__(192) void k_xi(const float* __restrict__ xi0,
                                            const float* __restrict__ stats,
                                            const float* __restrict__ gnw, const float* __restrict__ gnb,
                                            const float* __restrict__ qw, const float* __restrict__ qb,
                                            float* __restrict__ xi) {
    int b = blockIdx.x / HHc, h = blockIdx.x % HHc;
    int w = threadIdx.x;
    const float Ninv = 1.f / (8.f * HWc);
    float tn[16];
#pragma unroll
    for (int n = 0; n < 16; ++n) {
        int g = n >> 3;
        float su = stats[(b * 2 + g) * 2], sq = stats[(b * 2 + g) * 2 + 1];
        float mu = su * Ninv;
        float var = sq * Ninv - mu * mu;
        float inv = rsqrtf(var + EPSc);
        float v = xi0[((size_t)b * NRk + n) * HWc + (size_t)h * WWc + w];
        tn[n] = (v - mu) * inv * gnw[n] + gnb[n];
    }
#pragma unroll
    for (int d = 0; d < 32; ++d) {
        float acc = qb[d];
        const float* row = qw + d * 16;
#pragma unroll
        for (int n = 0; n < 16; ++n) acc += tn[n] * row[n];
        xi[((size_t)b * CCc + d) * HWc + (size_t)h * WWc + w] = 1.f / (1.f + expf(-acc));
    }
}

// ---------------- DFT chain (z input: [b][D], batch stride D) ----------------
// plain forward DFT along W (used for eval 1 where z = F0 directly)
__global__ __launch_bounds__(192) void k_dftw(const float* __restrict__ z0,
                                              const float* __restrict__ tab,
                                              float* __restrict__ Zc) {
    int bc = blockIdx.x / 24;
    int hg = blockIdx.x % 24;
    int b = bc >> 5, c = bc & 31;
    const float* zp = z0 + (size_t)b * DDs + (size_t)c * HWc + (size_t)hg * 8 * WWc;
    __shared__ float rows[8 * 196];
    __shared__ float tb[24 * 196];
    const float4* zq = (const float4*)zp;
    for (int i4 = threadIdx.x; i4 < 384; i4 += 192) {
        float4 v = zq[i4];
        int r = i4 / 48, col = (i4 % 48) * 4;
        *(float4*)&rows[r * 196 + col] = v;
    }
    for (int i4 = threadIdx.x; i4 < 1152; i4 += 192) {
        int rr = i4 / 48, col = (i4 % 48) * 4;
        const float* src = (rr < 12) ? &tab[rr * 192 + col] : &tab[2496 + (rr - 12) * 192 + col];
        *(float4*)&tb[rr * 196 + col] = *(const float4*)src;
    }
    __syncthreads();
    int t = threadIdx.x;
    int r = t / 24, q = t % 24, ky = q >> 1, isim = q & 1;
    const float* tbp = tb + (isim ? (12 + ky) * 196 : ky * 196);
    const float* rowp = rows + r * 196;
    float a0 = 0.f, a1 = 0.f, a2 = 0.f, a3 = 0.f;
#pragma unroll
    for (int w2 = 0; w2 < WWc; w2 += 4) {
        a0 += rowp[w2] * tbp[w2];
        a1 += rowp[w2 + 1] * tbp[w2 + 1];
        a2 += rowp[w2 + 2] * tbp[w2 + 2];
        a3 += rowp[w2 + 3] * tbp[w2 + 3];
    }
    float acc = (a0 + a1) + (a2 + a3);
    if (isim) acc = -acc;
    int h = hg * 8 + r;
    Zc[(((size_t)bc * HHc + h) * M1c + ky) * 2 + isim] = acc;
}

// FUSED xnew + forward W-DFT
__global__ __launch_bounds__(192) void k_dftwx(const float* __restrict__ F,
                                               const float* __restrict__ alpha,
                                               const float* __restrict__ tab,
                                               float* __restrict__ xc,
                                               float* __restrict__ Zc) {
    int bc = blockIdx.x / 24;
    int hg = blockIdx.x % 24;
    int b = bc >> 5, c = bc & 31;
    size_t elem = (size_t)b * DDs + (size_t)c * HWc + (size_t)hg * 8 * WWc;
    int off4 = (int)(elem >> 2);
    const int sq4 = 1179648;  // SZ_T/4
    float a0 = alpha[b * 5], a1 = alpha[b * 5 + 1], a2 = alpha[b * 5 + 2];
    float a3 = alpha[b * 5 + 3], a4 = alpha[b * 5 + 4];
    __shared__ float rows[8 * 196];
    __shared__ float tb[24 * 196];
    const float4* F4 = (const float4*)F;
    float4* xc4 = (float4*)xc;
    for (int i4 = threadIdx.x; i4 < 384; i4 += 192) {
        float4 f0 = F4[off4 + i4];
        float4 f1 = F4[sq4 + off4 + i4];
        float4 f2 = F4[2 * sq4 + off4 + i4];
        float4 f3 = F4[3 * sq4 + off4 + i4];
        float4 f4v = F4[4 * sq4 + off4 + i4];
        float4 v;
        v.x = a0 * f0.x + a1 * f1.x + a2 * f2.x + a3 * f3.x + a4 * f4v.x;
        v.y = a0 * f0.y + a1 * f1.y + a2 * f2.y + a3 * f3.y + a4 * f4v.y;
        v.z = a0 * f0.z + a1 * f1.z + a2 * f2.z + a3 * f3.z + a4 * f4v.z;
        v.w = a0 * f0.w + a1 * f1.w + a2 * f2.w + a3 * f3.w + a4 * f4v.w;
        xc4[off4 + i4] = v;
        int r = i4 / 48, col = (i4 % 48) * 4;
        *(float4*)&rows[r * 196 + col] = v;
    }
    for (int i4 = threadIdx.x; i4 < 1152; i4 += 192) {
        int rr = i4 / 48, col = (i4 % 48) * 4;
        const float* src = (rr < 12) ? &tab[rr * 192 + col] : &tab[2496 + (rr - 12) * 192 + col];
        *(float4*)&tb[rr * 196 + col] = *(const float4*)src;
    }
    __syncthreads();
    int t = threadIdx.x;
    int r = t / 24, q = t % 24, ky = q >> 1, isim = q & 1;
    const float* tbp = tb + (isim ? (12 + ky) * 196 : ky * 196);
    const float* rowp = rows + r * 196;
    float a0s = 0.f, a1s = 0.f, a2s = 0.f, a3s = 0.f;
#pragma unroll
    for (int w2 = 0; w2 < WWc; w2 += 4) {
        a0s += rowp[w2] * tbp[w2];
        a1s += rowp[w2 + 1] * tbp[w2 + 1];
        a2s += rowp[w2 + 2] * tbp[w2 + 2];
        a3s += rowp[w2 + 3] * tbp[w2 + 3];
    }
    float acc = (a0s + a1s) + (a2s + a3s);
    if (isim) acc = -acc;
    int h = hg * 8 + r;
    Zc[(((size_t)bc * HHc + h) * M1c + ky) * 2 + isim] = acc;
}

__global__ __launch_bounds__(256) void k_dfth(const float* __restrict__ Zc,
                                              const float* __restrict__ tab,
                                              float* __restrict__ ZF) {
    int bc = blockIdx.x;
    __shared__ float zp[HHc * 12 * 2];
    const float4* src = (const float4*)(Zc + (size_t)bc * HHc * 12 * 2);
    for (int i4 = threadIdx.x; i4 < HHc * 6; i4 += 256)
        *(float4*)&zp[i4 * 4] = src[i4];
    __syncthreads();
    const float* tc = tab;
    const float* ts = tab + 2496;
    for (int oidx = threadIdx.x; oidx < 288; oidx += 256) {
        int j = oidx / 12, ky = oidx % 12;
        int k = (j < 12) ? j : 24 - j;
        float sgn = (j < 12) ? 1.f : -1.f;
        float re0 = 0.f, im0 = 0.f, re1 = 0.f, im1 = 0.f;
        for (int h = 0; h < HHc; h += 2) {
            float zr = zp[(h * 12 + ky) * 2], zi = zp[(h * 12 + ky) * 2 + 1];
            float cv = tc[k * 192 + h], sv = sgn * ts[k * 192 + h];
            re0 += zr * cv + zi * sv;
            im0 += zi * cv - zr * sv;
            float zr1 = zp[((h + 1) * 12 + ky) * 2], zi1 = zp[((h + 1) * 12 + ky) * 2 + 1];
            float cv1 = tc[k * 192 + h + 1], sv1 = sgn * ts[k * 192 + h + 1];
            re1 += zr1 * cv1 + zi1 * sv1;
            im1 += zi1 * cv1 - zr1 * sv1;
        }
        ZF[((size_t)bc * 288 + oidx) * 2] = re0 + re1;
        ZF[((size_t)bc * 288 + oidx) * 2 + 1] = im0 + im1;
    }
}

__global__ __launch_bounds__(64) void k_mix(const float* __restrict__ ZF,
                                            const float* __restrict__ wt,
                                            float* __restrict__ MO) {
    int b = blockIdx.x / 288, mode = blockIdx.x % 288;
    __shared__ float zin[64];
    int t = threadIdx.x;
    zin[t] = ZF[(((size_t)b * 32 + (t >> 1)) * 288 + mode) * 2 + (t & 1)];
    __syncthreads();
    int o = t >> 1, ri = t & 1;
    const float* wp = wt + (size_t)mode * 2048;
    float acc = 0.f;
#pragma unroll 8
    for (int i = 0; i < 32; ++i) {
        float ar = zin[2 * i], ai = zin[2 * i + 1];
        float wr = wp[(i * 32 + o) * 2], wi = wp[(i * 32 + o) * 2 + 1];
        acc += ri ? (ar * wi + ai * wr) : (ar * wr - ai * wi);
    }
    MO[(((size_t)b * 32 + o) * 288 + mode) * 2 + ri] = acc;
}

__global__ __launch_bounds__(256) void k_idfth(const float* __restrict__ MO,
                                               const float* __restrict__ tab,
                                               float* __restrict__ Tm) {
    int bo = blockIdx.x;
    __shared__ float mp[576];
    const float4* src = (const float4*)(MO + (size_t)bo * 576);
    for (int i4 = threadIdx.x; i4 < 144; i4 += 256)
        *(float4*)&mp[i4 * 4] = src[i4];
    __syncthreads();
    const float* tc = tab;
    const float* ts = tab + 2496;
    const float scale = 1.f / 192.f;
    for (int oidx = threadIdx.x; oidx < HHc * 12; oidx += 256) {
        int h = oidx / 12, ky = oidx % 12;
        float re = 0.f, im = 0.f;
#pragma unroll
        for (int j = 0; j < 24; ++j) {
            int k = (j < 12) ? j : 24 - j;
            float sgn = (j < 12) ? 1.f : -1.f;
            float mr = mp[(j * 12 + ky) * 2], mi = mp[(j * 12 + ky) * 2 + 1];
            float cv = tc[k * 192 + h], sv = sgn * ts[k * 192 + h];
            re += mr * cv - mi * sv;
            im += mr * sv + mi * cv;
        }
        Tm[((size_t)bo * HHc + h) * 24 + ky * 2] = re * scale;
        Tm[((size_t)bo * HHc + h) * 24 + ky * 2 + 1] = im * scale;
    }
}

// iDFT-W + y2(1x1 conv) + exact gelu + xi add -> sbuf (= dest F slot); gn1 stats.
// ONE block per (b,h), 384 threads = 48 w-quads x 8 o-quads (z staged once).
// LDS: zl 196 (float4-clean, broadcast reads), w0s 37 / tms 29 (odd strides:
// oq*4*37 mod 32 = oq*20 -> all 8 oq on distinct banks; scalar-staged).
__global__ __launch_bounds__(384) void k_f5(const float* __restrict__ z0,
                                            const float* __restrict__ Tm,
                                            const float* __restrict__ xi,
                                            const float* __restrict__ w0w,
                                            const float* __restrict__ w0b,
                                            const float* __restrict__ tab,
                                            float* __restrict__ sbuf,
                                            float* __restrict__ stats_e,
                                            int use_y1) {
    int h = blockIdx.x % HHc;
    int b = blockIdx.x / HHc;
    __shared__ float zl[32 * 196];     // padded stride 196 (float4-clean)
    __shared__ float w0s[32 * 37];     // odd stride 37 (conflict-free for 8 oq)
    __shared__ float tms[32 * 29];     // odd stride 29
    __shared__ float red[6][4];
    int tid = threadIdx.x;
    if (z0) {
        const float* zp = z0 + (size_t)b * DDs + (size_t)h * WWc;
        for (int i4 = tid; i4 < 32 * 48; i4 += 384) {
            int c = i4 / 48, q = (i4 % 48) * 4;
            float4 v = *(const float4*)(zp + (size_t)c * HWc + q);
            *(float4*)&zl[c * 196 + q] = v;
        }
        for (int i = tid; i < 1024; i += 384) {
            int oo = i >> 5, c = i & 31;
            w0s[oo * 37 + c] = w0w[oo * 32 + c];
        }
    }
    if (use_y1) {
        for (int i = tid; i < 768; i += 384) {
            int oo = i / 24, u = i % 24;
            tms[oo * 29 + u] = Tm[(((size_t)b * 32 + oo) * HHc + h) * 24 + u];
        }
    }
    __syncthreads();

    int wq = tid >> 3;          // 0..47
    int oq = tid & 7;           // 0..7
    int w4 = wq * 4;
    int o0 = oq * 4;            // o base (0..28)
    int grp = oq >> 2;          // GN group (all 4 o of this thread share it)
    const float Winv = 1.f / 192.f;
    float acc[4][4];
#pragma unroll
    for (int oo = 0; oo < 4; ++oo) {
        float bbv = w0b[o0 + oo];
#pragma unroll
        for (int k = 0; k < 4; ++k) acc[oo][k] = bbv;
    }
    if (use_y1) {
#pragma unroll
        for (int oo = 0; oo < 4; ++oo) {
            float t0 = tms[(o0 + oo) * 29];
#pragma unroll
            for (int k = 0; k < 4; ++k) acc[oo][k] += t0 * Winv;
        }
#pragma unroll
        for (int ky = 1; ky <= 11; ++ky) {
            float4 c4 = *(const float4*)(tab + ky * 192 + w4);
            float4 s4 = *(const float4*)(tab + 2496 + ky * 192 + w4);
            float sc = 2.f * Winv;
#pragma unroll
            for (int oo = 0; oo < 4; ++oo) {
                float tre = tms[(o0 + oo) * 29 + 2 * ky] * sc;
                float tim = tms[(o0 + oo) * 29 + 2 * ky + 1] * sc;
                acc[oo][0] += tre * c4.x - tim * s4.x;
                acc[oo][1] += tre * c4.y - tim * s4.y;
                acc[oo][2] += tre * c4.z - tim * s4.z;
                acc[oo][3] += tre * c4.w - tim * s4.w;
            }
        }
    }
    if (z0) {
#pragma unroll 8
        for (int c = 0; c < 32; ++c) {
            float4 zq4 = *(const float4*)&zl[c * 196 + w4];
#pragma unroll
            for (int oo = 0; oo < 4; ++oo) {
                float wv = w0s[(o0 + oo) * 37 + c];
                acc[oo][0] += zq4.x * wv;
                acc[oo][1] += zq4.y * wv;
                acc[oo][2] += zq4.z * wv;
                acc[oo][3] += zq4.w * wv;
            }
        }
    }
    float s = 0.f, q = 0.f;
#pragma unroll
    for (int oo = 0; oo < 4; ++oo) {
        int o = o0 + oo;
        size_t gi = (size_t)b * DDs + (size_t)o * HWc + (size_t)h * WWc + w4;
        float4 x4 = *(const float4*)(xi + gi);
        float4 out4;
        float* op = (float*)&out4;
        const float* xp = (const float*)&x4;
#pragma unroll
        for (int k = 0; k < 4; ++k) {
            float v = acc[oo][k];
            float u = 0.5f * v * (1.f + erff(v * 0.70710678118654752f));
            float sv = xp[k] + u;
            op[k] = sv;
            s += sv;
            q += sv * sv;
        }
        *(float4*)(sbuf + gi) = out4;
    }
    float s0 = (grp == 0) ? s : 0.f, q0 = (grp == 0) ? q : 0.f;
    float s1 = (grp == 1) ? s : 0.f, q1 = (grp == 1) ? q : 0.f;
    for (int o = 32; o; o >>= 1) {
        s0 += __shfl_down(s0, o); q0 += __shfl_down(q0, o);
        s1 += __shfl_down(s1, o); q1 += __shfl_down(q1, o);
    }
    int wid = tid >> 6, lane = tid & 63;
    if (lane == 0) { red[wid][0] = s0; red[wid][1] = q0; red[wid][2] = s1; red[wid][3] = q1; }
    __syncthreads();
    if (tid == 0) {
        float a0 = 0, a1 = 0, a2 = 0, a3 = 0;
        for (int i = 0; i < 6; ++i) {
            a0 += red[i][0]; a1 += red[i][1]; a2 += red[i][2]; a3 += red[i][3];
        }
        atomicAdd(&stats_e[b * 4 + 0], a0);
        atomicAdd(&stats_e[b * 4 + 1], a1);
        atomicAdd(&stats_e[b * 4 + 2], a2);
        atomicAdd(&stats_e[b * 4 + 3], a3);
    }
}

// buf = relu(z + GN1(buf)) IN PLACE (float4); gn2 stats; zero gram row/col of slot
// grid: 8 bins x 144 blocks of 256 threads. z0 == nullptr => z = 0.
__global__ __launch_bounds__(256) void k_f6(const float* __restrict__ z0,
                                            float* buf,
                                            const float* __restrict__ stats_e,
                                            const float* __restrict__ n1w,
                                            const float* __restrict__ n1b,
                                            float* __restrict__ gram,
                                            int slot) {
    if (blockIdx.x == 0 && threadIdx.x < 20) {
        int j = threadIdx.x % 5, b2 = threadIdx.x / 5;
        int ii = slot > j ? slot : j, jj = slot > j ? j : slot;
        gram[b2 * 15 + ii * (ii + 1) / 2 + jj] = 0.f;
    }
    const int binq = 147456;         // quads per bin (16*HWc/4)
    const int BPB = 144;
    int bin = blockIdx.x / BPB, sub = blockIdx.x % BPB;
    float Nv = 16.f * HWc;
    float su = stats_e[bin * 2], sq = stats_e[bin * 2 + 1];
    float mu = su / Nv;
    float var = sq / Nv - mu * mu;
    float inv = rsqrtf(var + EPSc);
    const float4* z4 = (const float4*)z0;
    float4* b4 = (float4*)buf;
    float s = 0.f, q = 0.f;
    for (int i4 = sub * 256 + threadIdx.x; i4 < binq; i4 += BPB * 256) {
        int e4 = bin * binq + i4;
        int c = (bin & 1) * 16 + i4 / 9216;    // 9216 = HWc/4
        float w1 = inv * n1w[c];
        float b1 = n1b[c] - mu * w1;
        float4 sv = b4[e4];
        float4 zv = make_float4(0.f, 0.f, 0.f, 0.f);
        if (z0) zv = z4[e4];
        float4 r;
        r.x = zv.x + sv.x * w1 + b1; r.x = r.x > 0.f ? r.x : 0.f;
        r.y = zv.y + sv.y * w1 + b1; r.y = r.y > 0.f ? r.y : 0.f;
        r.z = zv.z + sv.z * w1 + b1; r.z = r.z > 0.f ? r.z : 0.f;
        r.w = zv.w + sv.w * w1 + b1; r.w = r.w > 0.f ? r.w : 0.f;
        b4[e4] = r;
        s += r.x + r.y + r.z + r.w;
        q += r.x * r.x + r.y * r.y + r.z * r.z + r.w * r.w;
    }
    for (int o = 32; o; o >>= 1) { s += __shfl_down(s, o); q += __shfl_down(q, o); }
    __shared__ float rs[4], rq[4];
    int wid = threadIdx.x >> 6, lane = threadIdx.x & 63;
    if (lane == 0) { rs[wid] = s; rq[wid] = q; }
    __syncthreads();
    if (threadIdx.x == 0) {
        atomicAdd((float*)&stats_e[16 + bin * 2], rs[0] + rs[1] + rs[2] + rs[3]);
        atomicAdd((float*)&stats_e[16 + bin * 2 + 1], rq[0] + rq[1] + rq[2] + rq[3]);
    }
}

// buf = GN2(buf) IN PLACE; if do_gram: G[slot] = bf16(buf - z); incremental Gram.
// grid: 4 b x 288 sub = 1152 blocks of 256. z0 == nullptr => z = 0.
__global__ __launch_bounds__(256) void k_f7g(float* buf,
                                             const float* __restrict__ z,
                                             const float* __restrict__ stats_e,
                                             const float* __restrict__ n2w,
                                             const float* __restrict__ n2b,
                                             unsigned short* __restrict__ G,
                                             float* __restrict__ gram,
                                             int slot, int do_gram) {
    int b = blockIdx.x / 288, sub = blockIdx.x % 288;
    const float Ninv = 1.f / (16.f * HWc);
    float su0 = stats_e[16 + b * 4], sq0 = stats_e[16 + b * 4 + 1];
    float mu0 = su0 * Ninv, inv0 = rsqrtf(sq0 * Ninv - mu0 * mu0 + EPSc);
    float su1 = stats_e[16 + b * 4 + 2], sq1 = stats_e[16 + b * 4 + 3];
    float mu1 = su1 * Ninv, inv1 = rsqrtf(sq1 * Ninv - mu1 * mu1 + EPSc);
    const int bq = 294912;   // quads per batch (DDi/4)
    const int sq4 = 1179648; // quads per G slot (SZ_T/4)
    float4* b4 = (float4*)buf;
    const float4* z4 = (const float4*)z;
    ushort4* GU = (ushort4*)G;
    float p0 = 0, p1 = 0, p2 = 0, p3 = 0, p4 = 0;
    for (int loc4 = sub * 256 + threadIdx.x; loc4 < bq; loc4 += 73728) {
        int e4 = b * bq + loc4;
        int c = loc4 / 9216;
        float mu = (c < 16) ? mu0 : mu1;
        float inv = (c < 16) ? inv0 : inv1;
        float wv = inv * n2w[c];
        float bv = n2b[c] - mu * wv;
        float4 r = b4[e4];
        float4 fn;
        fn.x = r.x * wv + bv;
        fn.y = r.y * wv + bv;
        fn.z = r.z * wv + bv;
        fn.w = r.w * wv + bv;
        b4[e4] = fn;
        if (do_gram) {
            float4 zv = make_float4(0.f, 0.f, 0.f, 0.f);
            if (z) zv = z4[e4];
            float4 g;
            g.x = fn.x - zv.x; g.y = fn.y - zv.y; g.z = fn.z - zv.z; g.w = fn.w - zv.w;
            ushort4 gw;
            gw.x = f2bf(g.x); gw.y = f2bf(g.y); gw.z = f2bf(g.z); gw.w = f2bf(g.w);
            GU[(size_t)slot * sq4 + e4] = gw;
            float4 gj[5];
#pragma unroll
            for (int j = 0; j < 5; ++j) {
                if (j == slot) { gj[j] = g; }
                else {
                    ushort4 u = GU[(size_t)j * sq4 + e4];
                    gj[j].x = bf2f(u.x); gj[j].y = bf2f(u.y);
                    gj[j].z = bf2f(u.z); gj[j].w = bf2f(u.w);
                }
            }
            p0 += g.x * gj[0].x + g.y * gj[0].y + g.z * gj[0].z + g.w * gj[0].w;
            p1 += g.x * gj[1].x + g.y * gj[1].y + g.z * gj[1].z + g.w * gj[1].w;
            p2 += g.x * gj[2].x + g.y * gj[2].y + g.z * gj[2].z + g.w * gj[2].w;
            p3 += g.x * gj[3].x + g.y * gj[3].y + g.z * gj[3].z + g.w * gj[3].w;
            p4 += g.x * gj[4].x + g.y * gj[4].y + g.z * gj[4].z + g.w * gj[4].w;
        }
    }
    if (!do_gram) return;
    float p[5] = {p0, p1, p2, p3, p4};
    __shared__ float red[4][5];
    int wid = threadIdx.x >> 6, lane = threadIdx.x & 63;
#pragma unroll
    for (int j = 0; j < 5; ++j) {
        float v = p[j];
        for (int o = 32; o; o >>= 1) v += __shfl_down(v, o);
        if (lane == 0) red[wid][j] = v;
    }
    __syncthreads();
    if (threadIdx.x == 0) {
#pragma unroll
        for (int j = 0; j < 5; ++j) {
            int ii = slot > j ? slot : j, jj = slot > j ? j : slot;
            atomicAdd(&gram[b * 15 + ii * (ii + 1) / 2 + jj],
                      red[0][j] + red[1][j] + red[2][j] + red[3][j]);
        }
    }
}

// ---------------- Anderson solve (tiny, separate) ----------------
__global__ void k_solve(const float* __restrict__ gram, float* __restrict__ alpha, int n) {
    int b = threadIdx.x;
    if (b >= BBc) return;
    float A[6][7];
    int nn = n + 1;
    for (int i = 0; i < nn; ++i)
        for (int j = 0; j <= nn; ++j) A[i][j] = 0.f;
    for (int j = 1; j < nn; ++j) { A[0][j] = 1.f; A[j][0] = 1.f; }
    for (int i = 0; i < n; ++i)
        for (int j = 0; j < n; ++j) {
            int ii = i > j ? i : j, jj = i > j ? j : i;
            float v = gram[b * 15 + ii * (ii + 1) / 2 + jj];
            A[i + 1][j + 1] = v + ((i == j) ? 1e-4f : 0.f);
        }
    A[0][nn] = 1.f;
    for (int col = 0; col < nn; ++col) {
        int piv = col;
        float best = fabsf(A[col][col]);
        for (int r2 = col + 1; r2 < nn; ++r2) {
            float av = fabsf(A[r2][col]);
            if (av > best) { best = av; piv = r2; }
        }
        if (piv != col)
            for (int c2 = 0; c2 <= nn; ++c2) {
                float tv = A[col][c2];
                A[col][c2] = A[piv][c2];
                A[piv][c2] = tv;
            }
        float d = A[col][col];
        for (int r2 = col + 1; r2 < nn; ++r2) {
            float f = A[r2][col] / d;
            for (int c2 = col; c2 <= nn; ++c2) A[r2][c2] -= f * A[col][c2];
        }
    }
    float sol[6];
    for (int r2 = nn - 1; r2 >= 0; --r2) {
        float v = A[r2][nn];
        for (int c2 = r2 + 1; c2 < nn; ++c2) v -= A[r2][c2] * sol[c2];
        sol[r2] = v / A[r2][r2];
    }
    for (int j = 0; j < 5; ++j) alpha[b * 5 + j] = (j < n) ? sol[j + 1] : 0.f;
}

// ---------------- final: BN stats + BN + fc1(gelu) + fc2 ----------------
__global__ __launch_bounds__(256) void k_bnstats(const float* __restrict__ z,
                                                 float* __restrict__ bstats) {
    const int BPB = 18;
    int c = blockIdx.x / BPB, sub = blockIdx.x % BPB;
    float s = 0.f, q = 0.f;
    for (int i = sub * 256 + threadIdx.x; i < BBc * HWc; i += BPB * 256) {
        int b = i / HWc, hw = i % HWc;
        float v = z[(size_t)b * DDs + (size_t)c * HWc + hw];
        s += v;
        q += v * v;
    }
    for (int o = 32; o; o >>= 1) { s += __shfl_down(s, o); q += __shfl_down(q, o); }
    __shared__ float rs[4], rq[4];
    int wid = threadIdx.x >> 6, lane = threadIdx.x & 63;
    if (lane == 0) { rs[wid] = s; rq[wid] = q; }
    __syncthreads();
    if (threadIdx.x == 0) {
        atomicAdd(&bstats[c * 2], rs[0] + rs[1] + rs[2] + rs[3]);
        atomicAdd(&bstats[c * 2 + 1], rq[0] + rq[1] + rq[2] + rq[3]);
    }
}

__global__ __launch_bounds__(192) void k_final(const float* __restrict__ z,
                                               const float* __restrict__ bstats,
                                               const float* __restrict__ bnw,
                                               const float* __restrict__ bnb,
                                               const float* __restrict__ fc1w,
                                               const float* __restrict__ fc1b,
                                               const float* __restrict__ fc2w,
                                               const float* __restrict__ fc2b,
                                               float* __restrict__ out) {
    int b = blockIdx.x / HHc, h = blockIdx.x % HHc;
    int w = threadIdx.x;
    const float Ninv = 1.f / ((float)BBc * HWc);
    float zv[32];
#pragma unroll
    for (int c = 0; c < 32; ++c) {
        float su = bstats[c * 2], sq = bstats[c * 2 + 1];
        float mu = su * Ninv;
        float var = sq * Ninv - mu * mu;
        float inv = rsqrtf(var + EPSc);
        float v = z[(size_t)b * DDs + (size_t)c * HWc + (size_t)h * WWc + w];
        zv[c] = (v - mu) * inv * bnw[c] + bnb[c];
    }
    float acc2 = fc2b[0];
#pragma unroll
    for (int o = 0; o < 32; ++o) {
        float a = fc1b[o];
        const float* row = fc1w + o * 32;
#pragma unroll
        for (int c = 0; c < 32; ++c) a += zv[c] * row[c];
        float g = 0.5f * a * (1.f + erff(a * 0.70710678118654752f));
        acc2 += fc2w[o] * g;
    }
    out[(size_t)b * HWc + (size_t)h * WWc + w] = acc2;
}

// ---------------- host ----------------
extern "C" void kernel_launch(void* const* d_in, const int* in_sizes, int n_in,
                              void* d_out, int out_size, void* d_ws, size_t ws_size,
                              hipStream_t stream) {
    (void)in_sizes; (void)n_in; (void)out_size; (void)ws_size;
    const float* x    = (const float*)d_in[0];
    const float* fc0w = (const float*)d_in[1];
    const float* fc0b = (const float*)d_in[2];
    const float* convw = (const float*)d_in[3];
    const float* gnw  = (const float*)d_in[4];
    const float* gnb  = (const float*)d_in[5];
    const float* qw   = (const float*)d_in[6];
    const float* qb   = (const float*)d_in[7];
    const float* sw1r = (const float*)d_in[8];
    const float* sw1i = (const float*)d_in[9];
    const float* sw2r = (const float*)d_in[10];
    const float* sw2i = (const float*)d_in[11];
    const float* w0w  = (const float*)d_in[12];
    const float* w0b  = (const float*)d_in[13];
    const float* n1w  = (const float*)d_in[14];
    const float* n1b  = (const float*)d_in[15];
    const float* n2w  = (const float*)d_in[16];
    const float* n2b  = (const float*)d_in[17];
    const float* bnw  = (const float*)d_in[18];
    const float* bnb  = (const float*)d_in[19];
    const float* fc1w = (const float*)d_in[20];
    const float* fc1b = (const float*)d_in[21];
    const float* fc2w = (const float*)d_in[22];
    const float* fc2b = (const float*)d_in[23];
    float* out = (float*)d_out;

    float* ws = (float*)d_ws;
    float* XC  = ws + OFF_XC;
    float* XIp = ws + OFF_XI;
    float* Fb  = ws + OFF_F;
    unsigned short* Gb16 = (unsigned short*)(ws + OFF_G);
    float* ZC  = ws + OFF_ZC;
    float* ZFp = ws + OFF_ZF;
    float* MOp = ws + OFF_MO;
    float* TM  = ws + OFF_TM;
    float* WT  = ws + OFF_WT;
    float* TAB = ws + OFF_TAB;
    float* ST  = ws + OFF_STAT;
    float* XI0 = ws + A_XI0;   // setup alias (inside G region, dead before first f7g)
    float* EWB = MOp;          // setup alias (MO region free until DFT chain)

    // tail of one f_block evaluation (after ZC is ready or skipped)
    // zin == nullptr means z == 0 exactly (eval 0).
    auto runtail = [&](const float* zin, int outslot, int use_y1, int evalIdx,
                       int do_gram) {
        float* dst = Fb + (size_t)outslot * SZ_T;
        if (use_y1) {
            k_dfth<<<BBc * CCc, 256, 0, stream>>>(ZC, TAB, ZFp);
            k_mix<<<BBc * 288, 64, 0, stream>>>(ZFp, WT, MOp);
            k_idfth<<<BBc * CCc, 256, 0, stream>>>(MOp, TAB, TM);
        }
        float* stats_e = ST + (size_t)evalIdx * 32;
        k_f5<<<BBc * HHc, 384, 0, stream>>>(zin, TM, XIp, w0w, w0b, TAB, dst,
                                            stats_e, use_y1);
        k_f6<<<8 * 144, 256, 0, stream>>>(zin, dst, stats_e, n1w, n1b,
                                          ST + ST_GRAM, outslot);
        k_f7g<<<4 * 288, 256, 0, stream>>>(dst, zin, stats_e, n2w, n2b, Gb16,
                                           ST + ST_GRAM, outslot, do_gram);
    };

    // setup
    k_tables<<<10, 256, 0, stream>>>(TAB);
    k_wt<<<(24 * 12 * 1024 + 255) / 256, 256, 0, stream>>>(sw1r, sw1i, sw2r, sw2i, WT);
    k_zero<<<3, 256, 0, stream>>>(ST, ST_TOTAL);
    k_ew<<<1, 192, 0, stream>>>(convw, fc0w, fc0b, EWB);
    k_conv2<<<BBc * HHc, 192, 0, stream>>>(x, EWB, XI0);
    k_binstats<<<8 * 36, 256, 0, stream>>>(XI0, ST + ST_INJ, 8 * HWc, 36);
    k_xi<<<BBc * HHc, 192, 0, stream>>>(XI0, ST + ST_INJ, gnw, gnb, qw, qb, XIp);

    // f0 = f(0) -> F0 (z == 0: no spectral path, no z reads), G0, Gram(0,*)
    runtail(nullptr, 0, 0, 0, 1);
    // f1 = f(F0): plain dftw on F0
    k_dftw<<<BBc * CCc * 24, 192, 0, stream>>>(Fb, TAB, ZC);
    runtail(Fb, 1, 1, 1, 1);

    // Anderson iterations k = 2..15: solve -> fused xnew+dftw -> rest
    for (int k = 2; k < 16; ++k) {
        int n = k < 5 ? k : 5;
        int slot = k % 5;
        k_solve<<<1, 64, 0, stream>>>(ST + ST_GRAM, ST + ST_ALPHA, n);
        k_dftwx<<<BBc * CCc * 24, 192, 0, stream>>>(Fb, ST + ST_ALPHA, TAB, XC, ZC);
        runtail(XC, slot, 1, k, (k < 15) ? 1 : 0);
    }

    // final z = F slot 0; BatchNorm + fc1(gelu) + fc2
    k_bnstats<<<32 * 18, 256, 0, stream>>>(Fb, ST + ST_BN);
    k_final<<<BBc * HHc, 192, 0, stream>>>(Fb, ST + ST_BN, bnw, bnb, fc1w, fc1b,
                                           fc2w, fc2b, out);
}

// Round 18
// 3442.491 us; speedup vs baseline: 1.0147x; 1.0105x over previous
//
#include <hip/hip_runtime.h>
#include <math.h>

#ifndef M_PI
#define M_PI 3.14159265358979323846
#endif

#define BBc 4
#define CCc 32
#define NRk 16
#define HHc 192
#define WWc 192
#define HWc 36864
#define DDi 1179648
#define M1c 12
#define EPSc 1e-5f

static const size_t DDs = (size_t)DDi;

// ---------------- workspace layout (floats) ----------------
#define SZ_T   ((size_t)4718592)       // B*C*HW  (= B*D)
#define SZ_ZC  ((size_t)589824)        // B*C*H*12*2
#define SZ_ZF  ((size_t)73728)         // B*C*24*12*2
#define SZ_WT  ((size_t)589824)        // 24*12*32*32*2
#define SZ_TAB ((size_t)4992)          // 13*192*2

#define OFF_XC   ((size_t)0)                  // xcur      (B*D)
#define OFF_XI   (OFF_XC + SZ_T)              // xi        (B*D floats)
#define OFF_F    (OFF_XI + SZ_T)              // F history [slot][B][D], 5 slots (SoA)
#define OFF_G    (OFF_F + 5 * SZ_T)           // G history BF16 [slot][B][D], 5 slots (half region)
#define OFF_ZC   (OFF_G + 5 * SZ_T)
#define OFF_ZF   (OFF_ZC + SZ_ZC)
#define OFF_MO   (OFF_ZF + SZ_ZF)
#define OFF_TM   (OFF_MO + SZ_ZF)
#define OFF_WT   (OFF_TM + SZ_ZC)
#define OFF_TAB  (OFF_WT + SZ_WT)
#define OFF_STAT (OFF_TAB + SZ_TAB)
// total ~223.3 MiB (fits ws). setup scratch aliases G region:
#define A_XI0  OFF_G                   // B*16*HW (dead before first f7g write)
// ew/eb (288 floats) live in the MO region during setup (dead until DFT chain)

// stats sublayout (floats within STAT region)
// [0..511] : 16 evals x 32  (gn1: e*32 + b*4 + g*2 + j ; gn2: e*32 + 16 + ...)
#define ST_INJ   512   // 16
#define ST_BN    528   // 64
#define ST_GRAM  592   // 60  (4 batches x 15 packed lower-tri, PERSISTENT)
#define ST_ALPHA 652   // 20
#define ST_TOTAL 672

// bf16 helpers (RNE)
__device__ __forceinline__ float bf2f(unsigned short u) {
    return __uint_as_float(((unsigned int)u) << 16);
}
__device__ __forceinline__ unsigned short f2bf(float f) {
    unsigned int u = __float_as_uint(f);
    unsigned int r = (u + 0x7FFFu + ((u >> 16) & 1u)) >> 16;
    return (unsigned short)r;
}

// ---------------- small utility kernels ----------------
__global__ void k_zero(float* p, int n) {
    int i = blockIdx.x * blockDim.x + threadIdx.x;
    if (i < n) p[i] = 0.f;
}

__global__ void k_tables(float* tab) {
    int i = blockIdx.x * blockDim.x + threadIdx.x;  // 13*192
    if (i < 13 * 192) {
        int k = i / 192, x = i % 192;
        double th = 2.0 * M_PI * (double)(k * x) / 192.0;
        tab[i] = (float)cos(th);
        tab[13 * 192 + i] = (float)sin(th);
    }
}

// transpose spectral weights to wt[j][ky][i][o][2], j in 0..23
__global__ void k_wt(const float* __restrict__ w1r, const float* __restrict__ w1i,
                     const float* __restrict__ w2r, const float* __restrict__ w2i,
                     float* __restrict__ wt) {
    int idx = blockIdx.x * 256 + threadIdx.x;  // 24*12*32*32
    if (idx >= 24 * 12 * 1024) return;
    int o = idx & 31;
    int i = (idx >> 5) & 31;
    int ky = (idx >> 10) % 12;
    int j = idx / (12 * 1024);
    const float* wr;
    const float* wi;
    int x;
    if (j < 12) { wr = w1r; wi = w1i; x = j; }
    else        { wr = w2r; wi = w2i; x = j - 12; }
    int src = ((i * 32 + o) * 12 + x) * 12 + ky;
    size_t dst = (((size_t)j * 12 + ky) * 1024 + i * 32 + o) * 2;
    wt[dst] = wr[src];
    wt[dst + 1] = wi[src];
}

// effective single-channel conv weights: ew[n][t] = sum_c cw[n][c][t]*fc0w[c],
// eb[n][t] = sum_c cw[n][c][t]*fc0b[c]   (rank-1 xin = x*fc0w + fc0b)
__global__ void k_ew(const float* __restrict__ cw, const float* __restrict__ fc0w,
                     const float* __restrict__ fc0b, float* __restrict__ ewb) {
    int i = threadIdx.x;  // 144 = 16 n x 9 taps
    if (i >= 144) return;
    int n = i / 9, t = i % 9;
    float ew = 0.f, eb = 0.f;
    for (int c = 0; c < 32; ++c) {
        float k = cw[(size_t)(n * CCc + c) * 9 + t];
        ew += k * fc0w[c];
        eb += k * fc0b[c];
    }
    ewb[i] = ew;
    ewb[144 + i] = eb;
}

// conv3x3 SAME on rank-1 input via effective kernels: 1 channel in, 16 out.
// block per (b,h), 192 threads (one per w). Boundary: whole-xin zeroing => per-tap mask.
__global__ __launch_bounds__(192) void k_conv2(const float* __restrict__ x,
                                               const float* __restrict__ ewb,
                                               float* __restrict__ xi0) {
    int b = blockIdx.x / HHc, h = blockIdx.x % HHc;
    __shared__ float sm[3 * 194];
    __shared__ float ews[144], ebs[144];
    int w = threadIdx.x;
    for (int i = threadIdx.x; i < 3 * 194; i += 192) {
        int r = i / 194, col = (i % 194) - 1;
        int hr = h + r - 1;
        float v = 0.f;
        if (hr >= 0 && hr < HHc && col >= 0 && col < WWc)
            v = x[(size_t)b * HWc + (size_t)hr * WWc + col];
        sm[i] = v;
    }
    if (threadIdx.x < 144) {
        ews[threadIdx.x] = ewb[threadIdx.x];
        ebs[threadIdx.x] = ewb[144 + threadIdx.x];
    }
    __syncthreads();
    float xv[9], mk[9];
#pragma unroll
    for (int r = 0; r < 3; ++r) {
        int hr = h + r - 1;
        bool rok = (hr >= 0 && hr < HHc);
#pragma unroll
        for (int dx = 0; dx < 3; ++dx) {
            int wx = w + dx - 1;
            bool ok = rok && (wx >= 0) && (wx < WWc);
            xv[r * 3 + dx] = sm[r * 194 + (w + dx)];
            mk[r * 3 + dx] = ok ? 1.f : 0.f;
        }
    }
#pragma unroll
    for (int n = 0; n < 16; ++n) {
        float acc = 0.f;
#pragma unroll
        for (int t = 0; t < 9; ++t)
            acc += ews[n * 9 + t] * xv[t] + mk[t] * ebs[n * 9 + t];
        xi0[((size_t)b * NRk + n) * HWc + (size_t)h * WWc + w] = acc;
    }
}

// generic contiguous-bin sum/sumsq with atomics
__global__ void k_binstats(const float* __restrict__ src, float* __restrict__ stats,
                           int binsize, int blocksPerBin) {
    int bin = blockIdx.x / blocksPerBin, sub = blockIdx.x % blocksPerBin;
    const float* p = src + (size_t)bin * binsize;
    float s = 0.f, q = 0.f;
    for (int i = sub * blockDim.x + threadIdx.x; i < binsize; i += blocksPerBin * blockDim.x) {
        float v = p[i];
        s += v;
        q += v * v;
    }
    for (int o = 32; o; o >>= 1) { s += __shfl_down(s, o); q += __shfl_down(q, o); }
    __shared__ float rs[4], rq[4];
    int wid = threadIdx.x >> 6, lane = threadIdx.x & 63;
    if (lane == 0) { rs[wid] = s; rq[wid] = q; }
    __syncthreads();
    if (threadIdx.x == 0) {
        int nw = blockDim.x >> 6;
        float ts = 0.f, tq = 0.f;
        for (int i = 0; i < nw; ++i) { ts += rs[i]; tq += rq[i]; }
        atomicAdd(&stats[bin * 2], ts);
        atomicAdd(&stats[bin * 2 + 1], tq);
    }
}

// xi = sigmoid(q_w * GN(xi0) + q_b), block per (b,h), register-blocked (fp32)
__global__ __launch_bounds__(192) void k_xi(const float* __restrict__ xi0,
                                            const float* __restrict__ stats,
                                            const float* __restrict__ gnw, const float* __restrict__ gnb,
                                            const float* __restrict__ qw, const float* __restrict__ qb,
                                            float* __restrict__ xi) {
    int b = blockIdx.x / HHc, h = blockIdx.x % HHc;
    int w = threadIdx.x;
    const float Ninv = 1.f / (8.f * HWc);
    float tn[16];
#pragma unroll
    for (int n = 0; n < 16; ++n) {
        int g = n >> 3;
        float su = stats[(b * 2 + g) * 2], sq = stats[(b * 2 + g) * 2 + 1];
        float mu = su * Ninv;
        float var = sq * Ninv - mu * mu;
        float inv = rsqrtf(var + EPSc);
        float v = xi0[((size_t)b * NRk + n) * HWc + (size_t)h * WWc + w];
        tn[n] = (v - mu) * inv * gnw[n] + gnb[n];
    }
#pragma unroll
    for (int d = 0; d < 32; ++d) {
        float acc = qb[d];
        const float* row = qw + d * 16;
#pragma unroll
        for (int n = 0; n < 16; ++n) acc += tn[n] * row[n];
        xi[((size_t)b * CCc + d) * HWc + (size_t)h * WWc + w] = 1.f / (1.f + expf(-acc));
    }
}

// ---------------- DFT chain (z input: [b][D], batch stride D) ----------------
// plain forward DFT along W (used for eval 1 where z = F0 directly)
__global__ __launch_bounds__(192) void k_dftw(const float* __restrict__ z0,
                                              const float* __restrict__ tab,
                                              float* __restrict__ Zc) {
    int bc = blockIdx.x / 24;
    int hg = blockIdx.x % 24;
    int b = bc >> 5, c = bc & 31;
    const float* zp = z0 + (size_t)b * DDs + (size_t)c * HWc + (size_t)hg * 8 * WWc;
    __shared__ float rows[8 * 196];
    __shared__ float tb[24 * 196];
    const float4* zq = (const float4*)zp;
    for (int i4 = threadIdx.x; i4 < 384; i4 += 192) {
        float4 v = zq[i4];
        int r = i4 / 48, col = (i4 % 48) * 4;
        *(float4*)&rows[r * 196 + col] = v;
    }
    for (int i4 = threadIdx.x; i4 < 1152; i4 += 192) {
        int rr = i4 / 48, col = (i4 % 48) * 4;
        const float* src = (rr < 12) ? &tab[rr * 192 + col] : &tab[2496 + (rr - 12) * 192 + col];
        *(float4*)&tb[rr * 196 + col] = *(const float4*)src;
    }
    __syncthreads();
    int t = threadIdx.x;
    int r = t / 24, q = t % 24, ky = q >> 1, isim = q & 1;
    const float* tbp = tb + (isim ? (12 + ky) * 196 : ky * 196);
    const float* rowp = rows + r * 196;
    float a0 = 0.f, a1 = 0.f, a2 = 0.f, a3 = 0.f;
#pragma unroll
    for (int w2 = 0; w2 < WWc; w2 += 4) {
        a0 += rowp[w2] * tbp[w2];
        a1 += rowp[w2 + 1] * tbp[w2 + 1];
        a2 += rowp[w2 + 2] * tbp[w2 + 2];
        a3 += rowp[w2 + 3] * tbp[w2 + 3];
    }
    float acc = (a0 + a1) + (a2 + a3);
    if (isim) acc = -acc;
    int h = hg * 8 + r;
    Zc[(((size_t)bc * HHc + h) * M1c + ky) * 2 + isim] = acc;
}

// FUSED xnew + forward W-DFT
__global__ __launch_bounds__(192) void k_dftwx(const float* __restrict__ F,
                                               const float* __restrict__ alpha,
                                               const float* __restrict__ tab,
                                               float* __restrict__ xc,
                                               float* __restrict__ Zc) {
    int bc = blockIdx.x / 24;
    int hg = blockIdx.x % 24;
    int b = bc >> 5, c = bc & 31;
    size_t elem = (size_t)b * DDs + (size_t)c * HWc + (size_t)hg * 8 * WWc;
    int off4 = (int)(elem >> 2);
    const int sq4 = 1179648;  // SZ_T/4
    float a0 = alpha[b * 5], a1 = alpha[b * 5 + 1], a2 = alpha[b * 5 + 2];
    float a3 = alpha[b * 5 + 3], a4 = alpha[b * 5 + 4];
    __shared__ float rows[8 * 196];
    __shared__ float tb[24 * 196];
    const float4* F4 = (const float4*)F;
    float4* xc4 = (float4*)xc;
    for (int i4 = threadIdx.x; i4 < 384; i4 += 192) {
        float4 f0 = F4[off4 + i4];
        float4 f1 = F4[sq4 + off4 + i4];
        float4 f2 = F4[2 * sq4 + off4 + i4];
        float4 f3 = F4[3 * sq4 + off4 + i4];
        float4 f4v = F4[4 * sq4 + off4 + i4];
        float4 v;
        v.x = a0 * f0.x + a1 * f1.x + a2 * f2.x + a3 * f3.x + a4 * f4v.x;
        v.y = a0 * f0.y + a1 * f1.y + a2 * f2.y + a3 * f3.y + a4 * f4v.y;
        v.z = a0 * f0.z + a1 * f1.z + a2 * f2.z + a3 * f3.z + a4 * f4v.z;
        v.w = a0 * f0.w + a1 * f1.w + a2 * f2.w + a3 * f3.w + a4 * f4v.w;
        xc4[off4 + i4] = v;
        int r = i4 / 48, col = (i4 % 48) * 4;
        *(float4*)&rows[r * 196 + col] = v;
    }
    for (int i4 = threadIdx.x; i4 < 1152; i4 += 192) {
        int rr = i4 / 48, col = (i4 % 48) * 4;
        const float* src = (rr < 12) ? &tab[rr * 192 + col] : &tab[2496 + (rr - 12) * 192 + col];
        *(float4*)&tb[rr * 196 + col] = *(const float4*)src;
    }
    __syncthreads();
    int t = threadIdx.x;
    int r = t / 24, q = t % 24, ky = q >> 1, isim = q & 1;
    const float* tbp = tb + (isim ? (12 + ky) * 196 : ky * 196);
    const float* rowp = rows + r * 196;
    float a0s = 0.f, a1s = 0.f, a2s = 0.f, a3s = 0.f;
#pragma unroll
    for (int w2 = 0; w2 < WWc; w2 += 4) {
        a0s += rowp[w2] * tbp[w2];
        a1s += rowp[w2 + 1] * tbp[w2 + 1];
        a2s += rowp[w2 + 2] * tbp[w2 + 2];
        a3s += rowp[w2 + 3] * tbp[w2 + 3];
    }
    float acc = (a0s + a1s) + (a2s + a3s);
    if (isim) acc = -acc;
    int h = hg * 8 + r;
    Zc[(((size_t)bc * HHc + h) * M1c + ky) * 2 + isim] = acc;
}

__global__ __launch_bounds__(256) void k_dfth(const float* __restrict__ Zc,
                                              const float* __restrict__ tab,
                                              float* __restrict__ ZF) {
    int bc = blockIdx.x;
    __shared__ float zp[HHc * 12 * 2];
    const float4* src = (const float4*)(Zc + (size_t)bc * HHc * 12 * 2);
    for (int i4 = threadIdx.x; i4 < HHc * 6; i4 += 256)
        *(float4*)&zp[i4 * 4] = src[i4];
    __syncthreads();
    const float* tc = tab;
    const float* ts = tab + 2496;
    for (int oidx = threadIdx.x; oidx < 288; oidx += 256) {
        int j = oidx / 12, ky = oidx % 12;
        int k = (j < 12) ? j : 24 - j;
        float sgn = (j < 12) ? 1.f : -1.f;
        float re0 = 0.f, im0 = 0.f, re1 = 0.f, im1 = 0.f;
        for (int h = 0; h < HHc; h += 2) {
            float zr = zp[(h * 12 + ky) * 2], zi = zp[(h * 12 + ky) * 2 + 1];
            float cv = tc[k * 192 + h], sv = sgn * ts[k * 192 + h];
            re0 += zr * cv + zi * sv;
            im0 += zi * cv - zr * sv;
            float zr1 = zp[((h + 1) * 12 + ky) * 2], zi1 = zp[((h + 1) * 12 + ky) * 2 + 1];
            float cv1 = tc[k * 192 + h + 1], sv1 = sgn * ts[k * 192 + h + 1];
            re1 += zr1 * cv1 + zi1 * sv1;
            im1 += zi1 * cv1 - zr1 * sv1;
        }
        ZF[((size_t)bc * 288 + oidx) * 2] = re0 + re1;
        ZF[((size_t)bc * 288 + oidx) * 2 + 1] = im0 + im1;
    }
}

__global__ __launch_bounds__(64) void k_mix(const float* __restrict__ ZF,
                                            const float* __restrict__ wt,
                                            float* __restrict__ MO) {
    int b = blockIdx.x / 288, mode = blockIdx.x % 288;
    __shared__ float zin[64];
    int t = threadIdx.x;
    zin[t] = ZF[(((size_t)b * 32 + (t >> 1)) * 288 + mode) * 2 + (t & 1)];
    __syncthreads();
    int o = t >> 1, ri = t & 1;
    const float* wp = wt + (size_t)mode * 2048;
    float acc = 0.f;
#pragma unroll 8
    for (int i = 0; i < 32; ++i) {
        float ar = zin[2 * i], ai = zin[2 * i + 1];
        float wr = wp[(i * 32 + o) * 2], wi = wp[(i * 32 + o) * 2 + 1];
        acc += ri ? (ar * wi + ai * wr) : (ar * wr - ai * wi);
    }
    MO[(((size_t)b * 32 + o) * 288 + mode) * 2 + ri] = acc;
}

__global__ __launch_bounds__(256) void k_idfth(const float* __restrict__ MO,
                                               const float* __restrict__ tab,
                                               float* __restrict__ Tm) {
    int bo = blockIdx.x;
    __shared__ float mp[576];
    const float4* src = (const float4*)(MO + (size_t)bo * 576);
    for (int i4 = threadIdx.x; i4 < 144; i4 += 256)
        *(float4*)&mp[i4 * 4] = src[i4];
    __syncthreads();
    const float* tc = tab;
    const float* ts = tab + 2496;
    const float scale = 1.f / 192.f;
    for (int oidx = threadIdx.x; oidx < HHc * 12; oidx += 256) {
        int h = oidx / 12, ky = oidx % 12;
        float re = 0.f, im = 0.f;
#pragma unroll
        for (int j = 0; j < 24; ++j) {
            int k = (j < 12) ? j : 24 - j;
            float sgn = (j < 12) ? 1.f : -1.f;
            float mr = mp[(j * 12 + ky) * 2], mi = mp[(j * 12 + ky) * 2 + 1];
            float cv = tc[k * 192 + h], sv = sgn * ts[k * 192 + h];
            re += mr * cv - mi * sv;
            im += mr * sv + mi * cv;
        }
        Tm[((size_t)bo * HHc + h) * 24 + ky * 2] = re * scale;
        Tm[((size_t)bo * HHc + h) * 24 + ky * 2 + 1] = im * scale;
    }
}

// iDFT-W + y2(1x1 conv) + exact gelu + xi add -> sbuf (= dest F slot); gn1 stats.
// block = (b, h, og): 2 blocks per (b,h). LDS: zl 196, w0s 36, tms 28 (padded).
// z0 == nullptr => z is exactly zero (eval 0): skip staging + y2 entirely.
__global__ __launch_bounds__(192) void k_f5(const float* __restrict__ z0,
                                            const float* __restrict__ Tm,
                                            const float* __restrict__ xi,
                                            const float* __restrict__ w0w,
                                            const float* __restrict__ w0b,
                                            const float* __restrict__ tab,
                                            float* __restrict__ sbuf,
                                            float* __restrict__ stats_e,
                                            int use_y1) {
    int bi = blockIdx.x;
    int og = bi & 1;
    int h = (bi >> 1) % HHc;
    int b = (bi >> 1) / HHc;
    __shared__ float zl[32 * 196];     // padded stride 196 (float4-clean)
    __shared__ float w0s[16 * 36];     // padded stride 36
    __shared__ float tms[16 * 28];     // padded stride 28
    __shared__ float red[3][2];
    int tid = threadIdx.x;
    if (z0) {
        const float* zp = z0 + (size_t)b * DDs + (size_t)h * WWc;
        for (int i4 = tid; i4 < 32 * 48; i4 += 192) {
            int c = i4 / 48, q = (i4 % 48) * 4;
            float4 v = *(const float4*)(zp + (size_t)c * HWc + q);
            *(float4*)&zl[c * 196 + q] = v;
        }
        for (int i4 = tid; i4 < 128; i4 += 192) {
            int oo = i4 / 8, q = (i4 % 8) * 4;
            *(float4*)&w0s[oo * 36 + q] = *(const float4*)(w0w + (og * 16 + oo) * 32 + q);
        }
    }
    if (use_y1) {
        for (int i4 = tid; i4 < 96; i4 += 192) {
            int oo = i4 / 6, q = (i4 % 6) * 4;
            int o = og * 16 + oo;
            *(float4*)&tms[oo * 28 + q] =
                *(const float4*)(Tm + (((size_t)b * 32 + o) * HHc + h) * 24 + q);
        }
    }
    __syncthreads();

    int wq = tid >> 2;          // 0..47
    int oq = tid & 3;           // 0..3
    int w4 = wq * 4;
    int lo0 = oq * 4;           // local o base (0..12)
    const float Winv = 1.f / 192.f;
    float acc[4][4];
#pragma unroll
    for (int oo = 0; oo < 4; ++oo) {
        float bbv = w0b[og * 16 + lo0 + oo];
#pragma unroll
        for (int k = 0; k < 4; ++k) acc[oo][k] = bbv;
    }
    if (use_y1) {
#pragma unroll
        for (int oo = 0; oo < 4; ++oo) {
            float t0 = tms[(lo0 + oo) * 28];
#pragma unroll
            for (int k = 0; k < 4; ++k) acc[oo][k] += t0 * Winv;
        }
#pragma unroll
        for (int ky = 1; ky <= 11; ++ky) {
            float4 c4 = *(const float4*)(tab + ky * 192 + w4);
            float4 s4 = *(const float4*)(tab + 2496 + ky * 192 + w4);
            float sc = 2.f * Winv;
#pragma unroll
            for (int oo = 0; oo < 4; ++oo) {
                float tre = tms[(lo0 + oo) * 28 + 2 * ky] * sc;
                float tim = tms[(lo0 + oo) * 28 + 2 * ky + 1] * sc;
                acc[oo][0] += tre * c4.x - tim * s4.x;
                acc[oo][1] += tre * c4.y - tim * s4.y;
                acc[oo][2] += tre * c4.z - tim * s4.z;
                acc[oo][3] += tre * c4.w - tim * s4.w;
            }
        }
    }
    if (z0) {
#pragma unroll 8
        for (int c = 0; c < 32; ++c) {
            float4 zq4 = *(const float4*)&zl[c * 196 + w4];
#pragma unroll
            for (int oo = 0; oo < 4; ++oo) {
                float wv = w0s[(lo0 + oo) * 36 + c];
                acc[oo][0] += zq4.x * wv;
                acc[oo][1] += zq4.y * wv;
                acc[oo][2] += zq4.z * wv;
                acc[oo][3] += zq4.w * wv;
            }
        }
    }
    float s = 0.f, q = 0.f;
#pragma unroll
    for (int oo = 0; oo < 4; ++oo) {
        int o = og * 16 + lo0 + oo;
        size_t gi = (size_t)b * DDs + (size_t)o * HWc + (size_t)h * WWc + w4;
        float4 x4 = *(const float4*)(xi + gi);
        float4 out4;
        float* op = (float*)&out4;
        const float* xp = (const float*)&x4;
#pragma unroll
        for (int k = 0; k < 4; ++k) {
            float v = acc[oo][k];
            float u = 0.5f * v * (1.f + erff(v * 0.70710678118654752f));
            float sv = xp[k] + u;
            op[k] = sv;
            s += sv;
            q += sv * sv;
        }
        *(float4*)(sbuf + gi) = out4;
    }
    for (int o = 32; o; o >>= 1) { s += __shfl_down(s, o); q += __shfl_down(q, o); }
    int wid = tid >> 6, lane = tid & 63;
    if (lane == 0) { red[wid][0] = s; red[wid][1] = q; }
    __syncthreads();
    if (tid == 0) {
        atomicAdd(&stats_e[b * 4 + og * 2], red[0][0] + red[1][0] + red[2][0]);
        atomicAdd(&stats_e[b * 4 + og * 2 + 1], red[0][1] + red[1][1] + red[2][1]);
    }
}

// buf = relu(z + GN1(buf)) IN PLACE (float4); gn2 stats; zero gram row/col of slot
// grid: 8 bins x 144 blocks of 256 threads. z0 == nullptr => z = 0.
__global__ __launch_bounds__(256) void k_f6(const float* __restrict__ z0,
                                            float* buf,
                                            const float* __restrict__ stats_e,
                                            const float* __restrict__ n1w,
                                            const float* __restrict__ n1b,
                                            float* __restrict__ gram,
                                            int slot) {
    if (blockIdx.x == 0 && threadIdx.x < 20) {
        int j = threadIdx.x % 5, b2 = threadIdx.x / 5;
        int ii = slot > j ? slot : j, jj = slot > j ? j : slot;
        gram[b2 * 15 + ii * (ii + 1) / 2 + jj] = 0.f;
    }
    const int binq = 147456;         // quads per bin (16*HWc/4)
    const int BPB = 144;
    int bin = blockIdx.x / BPB, sub = blockIdx.x % BPB;
    float Nv = 16.f * HWc;
    float su = stats_e[bin * 2], sq = stats_e[bin * 2 + 1];
    float mu = su / Nv;
    float var = sq / Nv - mu * mu;
    float inv = rsqrtf(var + EPSc);
    const float4* z4 = (const float4*)z0;
    float4* b4 = (float4*)buf;
    float s = 0.f, q = 0.f;
    for (int i4 = sub * 256 + threadIdx.x; i4 < binq; i4 += BPB * 256) {
        int e4 = bin * binq + i4;
        int c = (bin & 1) * 16 + i4 / 9216;    // 9216 = HWc/4
        float w1 = inv * n1w[c];
        float b1 = n1b[c] - mu * w1;
        float4 sv = b4[e4];
        float4 zv = make_float4(0.f, 0.f, 0.f, 0.f);
        if (z0) zv = z4[e4];
        float4 r;
        r.x = zv.x + sv.x * w1 + b1; r.x = r.x > 0.f ? r.x : 0.f;
        r.y = zv.y + sv.y * w1 + b1; r.y = r.y > 0.f ? r.y : 0.f;
        r.z = zv.z + sv.z * w1 + b1; r.z = r.z > 0.f ? r.z : 0.f;
        r.w = zv.w + sv.w * w1 + b1; r.w = r.w > 0.f ? r.w : 0.f;
        b4[e4] = r;
        s += r.x + r.y + r.z + r.w;
        q += r.x * r.x + r.y * r.y + r.z * r.z + r.w * r.w;
    }
    for (int o = 32; o; o >>= 1) { s += __shfl_down(s, o); q += __shfl_down(q, o); }
    __shared__ float rs[4], rq[4];
    int wid = threadIdx.x >> 6, lane = threadIdx.x & 63;
    if (lane == 0) { rs[wid] = s; rq[wid] = q; }
    __syncthreads();
    if (threadIdx.x == 0) {
        atomicAdd((float*)&stats_e[16 + bin * 2], rs[0] + rs[1] + rs[2] + rs[3]);
        atomicAdd((float*)&stats_e[16 + bin * 2 + 1], rq[0] + rq[1] + rq[2] + rq[3]);
    }
}

// buf = GN2(buf) IN PLACE; if do_gram: G[slot] = bf16(buf - z); incremental Gram.
// grid: 4 b x 288 sub = 1152 blocks of 256. z0 == nullptr => z = 0.
__global__ __launch_bounds__(256) void k_f7g(float* buf,
                                             const float* __restrict__ z,
                                             const float* __restrict__ stats_e,
                                             const float* __restrict__ n2w,
                                             const float* __restrict__ n2b,
                                             unsigned short* __restrict__ G,
                                             float* __restrict__ gram,
                                             int slot, int do_gram) {
    int b = blockIdx.x / 288, sub = blockIdx.x % 288;
    const float Ninv = 1.f / (16.f * HWc);
    float su0 = stats_e[16 + b * 4], sq0 = stats_e[16 + b * 4 + 1];
    float mu0 = su0 * Ninv, inv0 = rsqrtf(sq0 * Ninv - mu0 * mu0 + EPSc);
    float su1 = stats_e[16 + b * 4 + 2], sq1 = stats_e[16 + b * 4 + 3];
    float mu1 = su1 * Ninv, inv1 = rsqrtf(sq1 * Ninv - mu1 * mu1 + EPSc);
    const int bq = 294912;   // quads per batch (DDi/4)
    const int sq4 = 1179648; // quads per G slot (SZ_T/4)
    float4* b4 = (float4*)buf;
    const float4* z4 = (const float4*)z;
    ushort4* GU = (ushort4*)G;
    float p0 = 0, p1 = 0, p2 = 0, p3 = 0, p4 = 0;
    for (int loc4 = sub * 256 + threadIdx.x; loc4 < bq; loc4 += 73728) {
        int e4 = b * bq + loc4;
        int c = loc4 / 9216;
        float mu = (c < 16) ? mu0 : mu1;
        float inv = (c < 16) ? inv0 : inv1;
        float wv = inv * n2w[c];
        float bv = n2b[c] - mu * wv;
        float4 r = b4[e4];
        float4 fn;
        fn.x = r.x * wv + bv;
        fn.y = r.y * wv + bv;
        fn.z = r.z * wv + bv;
        fn.w = r.w * wv + bv;
        b4[e4] = fn;
        if (do_gram) {
            float4 zv = make_float4(0.f, 0.f, 0.f, 0.f);
            if (z) zv = z4[e4];
            float4 g;
            g.x = fn.x - zv.x; g.y = fn.y - zv.y; g.z = fn.z - zv.z; g.w = fn.w - zv.w;
            ushort4 gw;
            gw.x = f2bf(g.x); gw.y = f2bf(g.y); gw.z = f2bf(g.z); gw.w = f2bf(g.w);
            GU[(size_t)slot * sq4 + e4] = gw;
            float4 gj[5];
#pragma unroll
            for (int j = 0; j < 5; ++j) {
                if (j == slot) { gj[j] = g; }
                else {
                    ushort4 u = GU[(size_t)j * sq4 + e4];
                    gj[j].x = bf2f(u.x); gj[j].y = bf2f(u.y);
                    gj[j].z = bf2f(u.z); gj[j].w = bf2f(u.w);
                }
            }
            p0 += g.x * gj[0].x + g.y * gj[0].y + g.z * gj[0].z + g.w * gj[0].w;
            p1 += g.x * gj[1].x + g.y * gj[1].y + g.z * gj[1].z + g.w * gj[1].w;
            p2 += g.x * gj[2].x + g.y * gj[2].y + g.z * gj[2].z + g.w * gj[2].w;
            p3 += g.x * gj[3].x + g.y * gj[3].y + g.z * gj[3].z + g.w * gj[3].w;
            p4 += g.x * gj[4].x + g.y * gj[4].y + g.z * gj[4].z + g.w * gj[4].w;
        }
    }
    if (!do_gram) return;
    float p[5] = {p0, p1, p2, p3, p4};
    __shared__ float red[4][5];
    int wid = threadIdx.x >> 6, lane = threadIdx.x & 63;
#pragma unroll
    for (int j = 0; j < 5; ++j) {
        float v = p[j];
        for (int o = 32; o; o >>= 1) v += __shfl_down(v, o);
        if (lane == 0) red[wid][j] = v;
    }
    __syncthreads();
    if (threadIdx.x == 0) {
#pragma unroll
        for (int j = 0; j < 5; ++j) {
            int ii = slot > j ? slot : j, jj = slot > j ? j : slot;
            atomicAdd(&gram[b * 15 + ii * (ii + 1) / 2 + jj],
                      red[0][j] + red[1][j] + red[2][j] + red[3][j]);
        }
    }
}

// ---------------- Anderson solve (tiny, separate) ----------------
__global__ void k_solve(const float* __restrict__ gram, float* __restrict__ alpha, int n) {
    int b = threadIdx.x;
    if (b >= BBc) return;
    float A[6][7];
    int nn = n + 1;
    for (int i = 0; i < nn; ++i)
        for (int j = 0; j <= nn; ++j) A[i][j] = 0.f;
    for (int j = 1; j < nn; ++j) { A[0][j] = 1.f; A[j][0] = 1.f; }
    for (int i = 0; i < n; ++i)
        for (int j = 0; j < n; ++j) {
            int ii = i > j ? i : j, jj = i > j ? j : i;
            float v = gram[b * 15 + ii * (ii + 1) / 2 + jj];
            A[i + 1][j + 1] = v + ((i == j) ? 1e-4f : 0.f);
        }
    A[0][nn] = 1.f;
    for (int col = 0; col < nn; ++col) {
        int piv = col;
        float best = fabsf(A[col][col]);
        for (int r2 = col + 1; r2 < nn; ++r2) {
            float av = fabsf(A[r2][col]);
            if (av > best) { best = av; piv = r2; }
        }
        if (piv != col)
            for (int c2 = 0; c2 <= nn; ++c2) {
                float tv = A[col][c2];
                A[col][c2] = A[piv][c2];
                A[piv][c2] = tv;
            }
        float d = A[col][col];
        for (int r2 = col + 1; r2 < nn; ++r2) {
            float f = A[r2][col] / d;
            for (int c2 = col; c2 <= nn; ++c2) A[r2][c2] -= f * A[col][c2];
        }
    }
    float sol[6];
    for (int r2 = nn - 1; r2 >= 0; --r2) {
        float v = A[r2][nn];
        for (int c2 = r2 + 1; c2 < nn; ++c2) v -= A[r2][c2] * sol[c2];
        sol[r2] = v / A[r2][r2];
    }
    for (int j = 0; j < 5; ++j) alpha[b * 5 + j] = (j < n) ? sol[j + 1] : 0.f;
}

// ---------------- final: BN stats + BN + fc1(gelu) + fc2 ----------------
__global__ __launch_bounds__(256) void k_bnstats(const float* __restrict__ z,
                                                 float* __restrict__ bstats) {
    const int BPB = 18;
    int c = blockIdx.x / BPB, sub = blockIdx.x % BPB;
    float s = 0.f, q = 0.f;
    for (int i = sub * 256 + threadIdx.x; i < BBc * HWc; i += BPB * 256) {
        int b = i / HWc, hw = i % HWc;
        float v = z[(size_t)b * DDs + (size_t)c * HWc + hw];
        s += v;
        q += v * v;
    }
    for (int o = 32; o; o >>= 1) { s += __shfl_down(s, o); q += __shfl_down(q, o); }
    __shared__ float rs[4], rq[4];
    int wid = threadIdx.x >> 6, lane = threadIdx.x & 63;
    if (lane == 0) { rs[wid] = s; rq[wid] = q; }
    __syncthreads();
    if (threadIdx.x == 0) {
        atomicAdd(&bstats[c * 2], rs[0] + rs[1] + rs[2] + rs[3]);
        atomicAdd(&bstats[c * 2 + 1], rq[0] + rq[1] + rq[2] + rq[3]);
    }
}

__global__ __launch_bounds__(192) void k_final(const float* __restrict__ z,
                                               const float* __restrict__ bstats,
                                               const float* __restrict__ bnw,
                                               const float* __restrict__ bnb,
                                               const float* __restrict__ fc1w,
                                               const float* __restrict__ fc1b,
                                               const float* __restrict__ fc2w,
                                               const float* __restrict__ fc2b,
                                               float* __restrict__ out) {
    int b = blockIdx.x / HHc, h = blockIdx.x % HHc;
    int w = threadIdx.x;
    const float Ninv = 1.f / ((float)BBc * HWc);
    float zv[32];
#pragma unroll
    for (int c = 0; c < 32; ++c) {
        float su = bstats[c * 2], sq = bstats[c * 2 + 1];
        float mu = su * Ninv;
        float var = sq * Ninv - mu * mu;
        float inv = rsqrtf(var + EPSc);
        float v = z[(size_t)b * DDs + (size_t)c * HWc + (size_t)h * WWc + w];
        zv[c] = (v - mu) * inv * bnw[c] + bnb[c];
    }
    float acc2 = fc2b[0];
#pragma unroll
    for (int o = 0; o < 32; ++o) {
        float a = fc1b[o];
        const float* row = fc1w + o * 32;
#pragma unroll
        for (int c = 0; c < 32; ++c) a += zv[c] * row[c];
        float g = 0.5f * a * (1.f + erff(a * 0.70710678118654752f));
        acc2 += fc2w[o] * g;
    }
    out[(size_t)b * HWc + (size_t)h * WWc + w] = acc2;
}

// ---------------- host ----------------
extern "C" void kernel_launch(void* const* d_in, const int* in_sizes, int n_in,
                              void* d_out, int out_size, void* d_ws, size_t ws_size,
                              hipStream_t stream) {
    (void)in_sizes; (void)n_in; (void)out_size; (void)ws_size;
    const float* x    = (const float*)d_in[0];
    const float* fc0w = (const float*)d_in[1];
    const float* fc0b = (const float*)d_in[2];
    const float* convw = (const float*)d_in[3];
    const float* gnw  = (const float*)d_in[4];
    const float* gnb  = (const float*)d_in[5];
    const float* qw   = (const float*)d_in[6];
    const float* qb   = (const float*)d_in[7];
    const float* sw1r = (const float*)d_in[8];
    const float* sw1i = (const float*)d_in[9];
    const float* sw2r = (const float*)d_in[10];
    const float* sw2i = (const float*)d_in[11];
    const float* w0w  = (const float*)d_in[12];
    const float* w0b  = (const float*)d_in[13];
    const float* n1w  = (const float*)d_in[14];
    const float* n1b  = (const float*)d_in[15];
    const float* n2w  = (const float*)d_in[16];
    const float* n2b  = (const float*)d_in[17];
    const float* bnw  = (const float*)d_in[18];
    const float* bnb  = (const float*)d_in[19];
    const float* fc1w = (const float*)d_in[20];
    const float* fc1b = (const float*)d_in[21];
    const float* fc2w = (const float*)d_in[22];
    const float* fc2b = (const float*)d_in[23];
    float* out = (float*)d_out;

    float* ws = (float*)d_ws;
    float* XC  = ws + OFF_XC;
    float* XIp = ws + OFF_XI;
    float* Fb  = ws + OFF_F;
    unsigned short* Gb16 = (unsigned short*)(ws + OFF_G);
    float* ZC  = ws + OFF_ZC;
    float* ZFp = ws + OFF_ZF;
    float* MOp = ws + OFF_MO;
    float* TM  = ws + OFF_TM;
    float* WT  = ws + OFF_WT;
    float* TAB = ws + OFF_TAB;
    float* ST  = ws + OFF_STAT;
    float* XI0 = ws + A_XI0;   // setup alias (inside G region, dead before first f7g)
    float* EWB = MOp;          // setup alias (MO region free until DFT chain)

    // tail of one f_block evaluation (after ZC is ready or skipped)
    // zin == nullptr means z == 0 exactly (eval 0).
    auto runtail = [&](const float* zin, int outslot, int use_y1, int evalIdx,
                       int do_gram) {
        float* dst = Fb + (size_t)outslot * SZ_T;
        if (use_y1) {
            k_dfth<<<BBc * CCc, 256, 0, stream>>>(ZC, TAB, ZFp);
            k_mix<<<BBc * 288, 64, 0, stream>>>(ZFp, WT, MOp);
            k_idfth<<<BBc * CCc, 256, 0, stream>>>(MOp, TAB, TM);
        }
        float* stats_e = ST + (size_t)evalIdx * 32;
        k_f5<<<BBc * HHc * 2, 192, 0, stream>>>(zin, TM, XIp, w0w, w0b, TAB, dst,
                                                stats_e, use_y1);
        k_f6<<<8 * 144, 256, 0, stream>>>(zin, dst, stats_e, n1w, n1b,
                                          ST + ST_GRAM, outslot);
        k_f7g<<<4 * 288, 256, 0, stream>>>(dst, zin, stats_e, n2w, n2b, Gb16,
                                           ST + ST_GRAM, outslot, do_gram);
    };

    // setup
    k_tables<<<10, 256, 0, stream>>>(TAB);
    k_wt<<<(24 * 12 * 1024 + 255) / 256, 256, 0, stream>>>(sw1r, sw1i, sw2r, sw2i, WT);
    k_zero<<<3, 256, 0, stream>>>(ST, ST_TOTAL);
    k_ew<<<1, 192, 0, stream>>>(convw, fc0w, fc0b, EWB);
    k_conv2<<<BBc * HHc, 192, 0, stream>>>(x, EWB, XI0);
    k_binstats<<<8 * 36, 256, 0, stream>>>(XI0, ST + ST_INJ, 8 * HWc, 36);
    k_xi<<<BBc * HHc, 192, 0, stream>>>(XI0, ST + ST_INJ, gnw, gnb, qw, qb, XIp);

    // f0 = f(0) -> F0 (z == 0: no spectral path, no z reads), G0, Gram(0,*)
    runtail(nullptr, 0, 0, 0, 1);
    // f1 = f(F0): plain dftw on F0
    k_dftw<<<BBc * CCc * 24, 192, 0, stream>>>(Fb, TAB, ZC);
    runtail(Fb, 1, 1, 1, 1);

    // Anderson iterations k = 2..15: solve -> fused xnew+dftw -> rest
    for (int k = 2; k < 16; ++k) {
        int n = k < 5 ? k : 5;
        int slot = k % 5;
        k_solve<<<1, 64, 0, stream>>>(ST + ST_GRAM, ST + ST_ALPHA, n);
        k_dftwx<<<BBc * CCc * 24, 192, 0, stream>>>(Fb, ST + ST_ALPHA, TAB, XC, ZC);
        runtail(XC, slot, 1, k, (k < 15) ? 1 : 0);
    }

    // final z = F slot 0; BatchNorm + fc1(gelu) + fc2
    k_bnstats<<<32 * 18, 256, 0, stream>>>(Fb, ST + ST_BN);
    k_final<<<BBc * HHc, 192, 0, stream>>>(Fb, ST + ST_BN, bnw, bnb, fc1w, fc1b,
                                           fc2w, fc2b, out);
}